// Round 1
// baseline (872.219 us; speedup 1.0000x reference)
//
#include <hip/hip_runtime.h>
#include <math.h>

#define D_MODELC 128
#define NSAMP 8
#define DFF 512
#define NCROSS 3
#define NSELF 2
#define PREDN 4
#define BB 2
#define NCAM 5
#define QQ 2500
#define HFI 24
#define WFI 77
#define VXC 32
#define VYC 16
#define VZC 32
#define BQ (BB*QQ)

// ---------------- helpers ----------------
__device__ __forceinline__ float blocksum128(float v, float* red2) {
#pragma unroll
  for (int off = 32; off > 0; off >>= 1) v += __shfl_down(v, off);
  int lane = threadIdx.x & 63;
  int w = threadIdx.x >> 6;
  if (lane == 0) red2[w] = v;
  __syncthreads();
  float r = red2[0] + red2[1];
  __syncthreads();
  return r;
}

// ---------------- mask dtype detection ----------------
// bool may arrive as u8 (raw numpy bool) or int32. For i32 0/1 data, bytes at
// offsets %4!=0 are always 0; for u8 random 0/1, ~half are 1.
__global__ void detect_mask_k(const unsigned char* __restrict__ m, int* __restrict__ flag) {
  __shared__ int f;
  if (threadIdx.x == 0) f = 0;
  __syncthreads();
  const int total = BB * NCAM * QQ;  // bytes if u8 (safe lower bound either way)
  for (int i = threadIdx.x; i < total; i += blockDim.x)
    if ((i & 3) && m[i]) f = 1;
  __syncthreads();
  if (threadIdx.x == 0) *flag = f;
}

__device__ __forceinline__ bool mask_at(const unsigned char* m, const int* flag, int idx) {
  if (*flag) return m[idx] != 0;
  return ((const int*)m)[idx] != 0;
}

// ---------------- precompute per-(b,q) mask stats ----------------
__global__ void precompute_k(const unsigned char* __restrict__ maskp, const int* __restrict__ flag,
                             float* __restrict__ mcnt, float* __restrict__ invden,
                             float* __restrict__ many) {
  int i = blockIdx.x * blockDim.x + threadIdx.x;
  if (i >= BQ) return;
  int b = i / QQ, q = i % QQ;
  float cnt = 0.f;
  for (int n = 0; n < NCAM; ++n)
    cnt += mask_at(maskp, flag, (b * NCAM + n) * QQ + q) ? 1.f : 0.f;
  mcnt[i] = cnt;
  invden[i] = 1.f / (cnt + 1e-6f);
  many[i] = cnt > 0.f ? 1.f : 0.f;
}

// ---------------- image feature transpose [BN,C,H,W] -> [BN,H,W,C] ----------------
__global__ void transpose_img_k(const float* __restrict__ in, float* __restrict__ out) {
  int idx = blockIdx.x * blockDim.x + threadIdx.x;
  const int total = BB * NCAM * D_MODELC * HFI * WFI;
  if (idx >= total) return;
  int c = idx & 127;
  int r = idx >> 7;           // bn*H*W + y*W + x
  int x = r % WFI;
  int t2 = r / WFI;
  int y = t2 % HFI;
  int bn = t2 / HFI;
  out[idx] = in[((size_t)(bn * D_MODELC + c) * HFI + y) * WFI + x];
}

// ---------------- fused LN + small projections (cross) ----------------
// outputs dp [BQ,16] and softmaxed att [BQ,8]
__global__ void ln_proj_cross_k(const float* __restrict__ qb,
                                const float* __restrict__ g, const float* __restrict__ bb,
                                const float* __restrict__ dpw, const float* __restrict__ dpb,
                                const float* __restrict__ aw, const float* __restrict__ ab,
                                float* __restrict__ dp_out, float* __restrict__ att_out) {
  __shared__ float red2[2];
  __shared__ float sln[128];
  __shared__ float part[4][32];
  __shared__ float attv[8];
  int row = blockIdx.x, t = threadIdx.x;
  float x = qb[row * 128 + t];
  float mu = blocksum128(x, red2) * (1.f / 128.f);
  float d = x - mu;
  float var = blocksum128(d * d, red2) * (1.f / 128.f);
  sln[t] = d * rsqrtf(var + 1e-5f) * g[t] + bb[t];
  __syncthreads();
  int col = t & 31, grp = t >> 5;
  float p = 0.f;
  if (col < 24) {
    int k0 = grp * 32;
    for (int k = k0; k < k0 + 32; ++k) {
      float w = (col < 16) ? dpw[k * 16 + col] : aw[k * 8 + (col - 16)];
      p += sln[k] * w;
    }
  }
  part[grp][col] = p;
  __syncthreads();
  if (t < 24) {
    float v = part[0][t] + part[1][t] + part[2][t] + part[3][t];
    if (t < 16) dp_out[row * 16 + t] = v + dpb[t];
    else attv[t - 16] = v + ab[t - 16];
  }
  __syncthreads();
  if (t == 0) {
    float mx = attv[0];
#pragma unroll
    for (int i = 1; i < 8; ++i) mx = fmaxf(mx, attv[i]);
    float e[8], s = 0.f;
#pragma unroll
    for (int i = 0; i < 8; ++i) { e[i] = expf(attv[i] - mx); s += e[i]; }
    float inv = 1.f / s;
#pragma unroll
    for (int i = 0; i < 8; ++i) att_out[row * 8 + i] = e[i] * inv;
  }
}

// ---------------- fused LN + small projections (self) ----------------
// outputs sampling coords g [BQ,24] (perm [1,0,2] applied, ref3d added) and att [BQ,8]
__global__ void ln_proj_self_k(const float* __restrict__ qb, const float* __restrict__ ref3d,
                               const float* __restrict__ g, const float* __restrict__ bb,
                               const float* __restrict__ dpw, const float* __restrict__ dpb,
                               const float* __restrict__ aw, const float* __restrict__ ab,
                               float* __restrict__ g_out, float* __restrict__ att_out) {
  __shared__ float red2[2];
  __shared__ float sln[128];
  __shared__ float part[4][32];
  __shared__ float attv[8];
  __shared__ float dpl[24];
  int row = blockIdx.x, t = threadIdx.x;
  float x = qb[row * 128 + t];
  float mu = blocksum128(x, red2) * (1.f / 128.f);
  float d = x - mu;
  float var = blocksum128(d * d, red2) * (1.f / 128.f);
  sln[t] = d * rsqrtf(var + 1e-5f) * g[t] + bb[t];
  __syncthreads();
  int col = t & 31, grp = t >> 5;
  float p = 0.f;
  {
    int k0 = grp * 32;
    for (int k = k0; k < k0 + 32; ++k) {
      float w = (col < 24) ? dpw[k * 24 + col] : aw[k * 8 + (col - 24)];
      p += sln[k] * w;
    }
  }
  part[grp][col] = p;
  __syncthreads();
  if (t < 32) {
    float v = part[0][t] + part[1][t] + part[2][t] + part[3][t];
    if (t < 24) dpl[t] = v + dpb[t];
    else attv[t - 24] = v + ab[t - 24];
  }
  __syncthreads();
  if (t == 0) {
    float mx = attv[0];
#pragma unroll
    for (int i = 1; i < 8; ++i) mx = fmaxf(mx, attv[i]);
    float e[8], s = 0.f;
#pragma unroll
    for (int i = 0; i < 8; ++i) { e[i] = expf(attv[i] - mx); s += e[i]; }
    float inv = 1.f / s;
#pragma unroll
    for (int i = 0; i < 8; ++i) att_out[row * 8 + i] = e[i] * inv;
  }
  if (t < 24) {
    int s_ = t / 3, j = t % 3;
    int pc = (j == 0) ? 1 : ((j == 1) ? 0 : 2);  // perm [1,0,2]
    g_out[row * 24 + t] = ref3d[row * 3 + pc] + dpl[s_ * 3 + pc];
  }
}

// ---------------- cross deformable sampling + (n,s) reduce ----------------
__global__ void cross_sample_k(const float* __restrict__ imgT, const float* __restrict__ refp,
                               const float* __restrict__ dp, const float* __restrict__ att,
                               const unsigned char* __restrict__ maskp, const int* __restrict__ flag,
                               float* __restrict__ R, float* __restrict__ Avec) {
  int row = blockIdx.x;
  int c = threadIdx.x;
  int b = row / QQ, q = row % QQ;
  __shared__ float dpl[16];
  __shared__ float al[8];
  if (c < 16) dpl[c] = dp[row * 16 + c];
  if (c < 8) al[c] = att[row * 8 + c];
  __syncthreads();
  float acc = 0.f, accA = 0.f;
  for (int n = 0; n < NCAM; ++n) {
    int mi = (b * NCAM + n) * QQ + q;
    if (!mask_at(maskp, flag, mi)) continue;
    float rx = refp[(size_t)mi * 2 + 0];
    float ry = refp[(size_t)mi * 2 + 1];
    const float* basep = imgT + (size_t)(b * NCAM + n) * HFI * WFI * 128;
    for (int s = 0; s < NSAMP; ++s) {
      float a = al[s];
      float px = (rx + dpl[s * 2 + 0]) * 2.f - 1.f;
      float py = (ry + dpl[s * 2 + 1]) * 2.f - 1.f;
      float fx = (px + 1.f) * 0.5f * (WFI - 1);
      float fy = (py + 1.f) * 0.5f * (HFI - 1);
      float x0f = floorf(fx), y0f = floorf(fy);
      int x0 = (int)x0f, y0 = (int)y0f;
      float xd = fx - x0f, yd = fy - y0f;
#pragma unroll
      for (int cy = 0; cy < 2; ++cy)
#pragma unroll
        for (int cx = 0; cx < 2; ++cx) {
          int xi = x0 + cx, yi = y0 + cy;
          if (xi < 0 || xi >= WFI || yi < 0 || yi >= HFI) continue;
          float w = (cx ? xd : 1.f - xd) * (cy ? yd : 1.f - yd);
          float aw_ = a * w;
          acc += aw_ * basep[((size_t)yi * WFI + xi) * 128 + c];
          accA += aw_;
        }
    }
  }
  R[(size_t)row * 128 + c] = acc;
  if (c == 0) Avec[row] = accA;
}

// ---------------- voxel scatter (last-q-wins, matching XLA-CPU in-order scatter) ----------------
__global__ void scatter_winner_k(const int* __restrict__ xi, const int* __restrict__ yi,
                                 const int* __restrict__ zi, int* __restrict__ winner) {
  int i = blockIdx.x * blockDim.x + threadIdx.x;
  if (i >= BQ) return;
  int b = i / QQ;
  int vox = yi[i] * (VXC * VZC) + xi[i] * VZC + zi[i];
  atomicMax(&winner[b * (VYC * VXC * VZC) + vox], i % QQ);
}

__global__ void scatter_write_k(const int* __restrict__ xi, const int* __restrict__ yi,
                                const int* __restrict__ zi, const int* __restrict__ winner,
                                const float* __restrict__ qb, float* __restrict__ vol) {
  int idx = blockIdx.x * blockDim.x + threadIdx.x;
  if (idx >= BQ * 128) return;
  int c = idx & 127;
  int row = idx >> 7;
  int b = row / QQ, q = row % QQ;
  int vox = yi[row] * (VXC * VZC) + xi[row] * VZC + zi[row];
  if (winner[b * (VYC * VXC * VZC) + vox] == q)
    vol[((size_t)b * (VYC * VXC * VZC) + vox) * 128 + c] = qb[idx];
}

// ---------------- 3d deformable sampling + s reduce ----------------
// vol layout [B][VY][VX][VZ][C]; grid x->W(VZ), y->H(VX), z->D(VY)
__global__ void self_sample_k(const float* __restrict__ vol, const float* __restrict__ gc,
                              const float* __restrict__ att, float* __restrict__ R3) {
  int row = blockIdx.x;
  int c = threadIdx.x;
  int b = row / QQ;
  __shared__ float gl[24];
  __shared__ float al[8];
  if (c < 24) gl[c] = gc[row * 24 + c];
  if (c < 8) al[c] = att[row * 8 + c];
  __syncthreads();
  const float* vb = vol + (size_t)b * (VYC * VXC * VZC) * 128;
  float acc = 0.f;
  for (int s = 0; s < NSAMP; ++s) {
    float a = al[s];
    float fx = (gl[s * 3 + 0] + 1.f) * 0.5f * (VZC - 1);
    float fy = (gl[s * 3 + 1] + 1.f) * 0.5f * (VXC - 1);
    float fz = (gl[s * 3 + 2] + 1.f) * 0.5f * (VYC - 1);
    float x0f = floorf(fx), y0f = floorf(fy), z0f = floorf(fz);
    int x0 = (int)x0f, y0 = (int)y0f, z0 = (int)z0f;
    float xd = fx - x0f, yd = fy - y0f, zd = fz - z0f;
#pragma unroll
    for (int cz = 0; cz < 2; ++cz)
#pragma unroll
      for (int cy = 0; cy < 2; ++cy)
#pragma unroll
        for (int cx = 0; cx < 2; ++cx) {
          int xip = x0 + cx, yip = y0 + cy, zip = z0 + cz;
          if (xip < 0 || xip >= VZC || yip < 0 || yip >= VXC || zip < 0 || zip >= VYC) continue;
          float w = (cx ? xd : 1.f - xd) * (cy ? yd : 1.f - yd) * (cz ? zd : 1.f - zd);
          acc += a * w * vb[(((size_t)zip * VXC + yip) * VZC + xip) * 128 + c];
        }
  }
  R3[(size_t)row * 128 + c] = acc;
}

// ---------------- generic f32 GEMM: out = [res +] op((A@W + bias*bscale) * oscale) ----------------
template <bool GELU, bool RES>
__global__ __launch_bounds__(256) void gemm_k(const float* __restrict__ A, const float* __restrict__ W,
                                              const float* __restrict__ bias,
                                              const float* __restrict__ bscale,
                                              const float* __restrict__ oscale,
                                              float* __restrict__ out, int M, int K, int N) {
  __shared__ float As[32][64];  // [k][m]
  __shared__ float Ws[32][64];  // [k][n]
  int m0 = blockIdx.x * 64, n0 = blockIdx.y * 64;
  int tid = threadIdx.x;
  float acc[4][4] = {};
  int mr = (tid >> 4) * 4;
  int nc = (tid & 15) * 4;
  for (int k0 = 0; k0 < K; k0 += 32) {
    {
      int r = tid >> 2;
      int kq = (tid & 3) * 8;
      int gm = m0 + r;
      float4 v0 = make_float4(0, 0, 0, 0), v1 = v0;
      if (gm < M) {
        const float* ap = A + (size_t)gm * K + k0 + kq;
        v0 = *(const float4*)ap;
        v1 = *(const float4*)(ap + 4);
      }
      As[kq + 0][r] = v0.x; As[kq + 1][r] = v0.y; As[kq + 2][r] = v0.z; As[kq + 3][r] = v0.w;
      As[kq + 4][r] = v1.x; As[kq + 5][r] = v1.y; As[kq + 6][r] = v1.z; As[kq + 7][r] = v1.w;
    }
    {
      int kr = tid >> 3;
      int nq = (tid & 7) * 8;
      const float* wp = W + (size_t)(k0 + kr) * N + n0 + nq;
      *(float4*)&Ws[kr][nq] = *(const float4*)wp;
      *(float4*)&Ws[kr][nq + 4] = *(const float4*)(wp + 4);
    }
    __syncthreads();
#pragma unroll
    for (int kk = 0; kk < 32; ++kk) {
      float4 av = *(const float4*)&As[kk][mr];
      float4 bv = *(const float4*)&Ws[kk][nc];
      float a_[4] = {av.x, av.y, av.z, av.w};
      float b_[4] = {bv.x, bv.y, bv.z, bv.w};
#pragma unroll
      for (int i = 0; i < 4; ++i)
#pragma unroll
        for (int j = 0; j < 4; ++j) acc[i][j] += a_[i] * b_[j];
    }
    __syncthreads();
  }
#pragma unroll
  for (int i = 0; i < 4; ++i) {
    int gm = m0 + mr + i;
    if (gm >= M) break;
    float bs = bscale ? bscale[gm] : 1.f;
    float os = oscale ? oscale[gm] : 1.f;
    float4 r;
    float* rp = &r.x;
#pragma unroll
    for (int j = 0; j < 4; ++j) {
      float v = acc[i][j] + bias[n0 + nc + j] * bs;
      v *= os;
      if (GELU) v = 0.5f * v * (1.f + erff(v * 0.70710678118654752f));
      rp[j] = v;
    }
    float* op = out + (size_t)gm * N + n0 + nc;
    if (RES) {
      float4 old = *(const float4*)op;
      r.x += old.x; r.y += old.y; r.z += old.z; r.w += old.w;
    }
    *(float4*)op = r;
  }
}

// ---------------- plain LayerNorm ----------------
__global__ void ln_k(const float* __restrict__ in, const float* __restrict__ g,
                     const float* __restrict__ b, float* __restrict__ out) {
  __shared__ float red2[2];
  int row = blockIdx.x, t = threadIdx.x;
  float x = in[row * 128 + t];
  float mu = blocksum128(x, red2) * (1.f / 128.f);
  float d = x - mu;
  float var = blocksum128(d * d, red2) * (1.f / 128.f);
  out[row * 128 + t] = d * rsqrtf(var + 1e-5f) * g[t] + b[t];
}

// ---------------- classifier ----------------
__global__ void classifier_k(const float* __restrict__ qb, const float* __restrict__ cw,
                             const float* __restrict__ cb, float* __restrict__ out) {
  __shared__ float red[2][4];
  int row = blockIdx.x, t = threadIdx.x;
  float v = qb[row * 128 + t];
  float p0 = v * cw[t * 4 + 0];
  float p1 = v * cw[t * 4 + 1];
  float p2 = v * cw[t * 4 + 2];
  float p3 = v * cw[t * 4 + 3];
#pragma unroll
  for (int off = 32; off > 0; off >>= 1) {
    p0 += __shfl_down(p0, off);
    p1 += __shfl_down(p1, off);
    p2 += __shfl_down(p2, off);
    p3 += __shfl_down(p3, off);
  }
  int lane = t & 63, w = t >> 6;
  if (lane == 0) { red[w][0] = p0; red[w][1] = p1; red[w][2] = p2; red[w][3] = p3; }
  __syncthreads();
  if (t < 4) out[row * 4 + t] = red[0][t] + red[1][t] + cb[t];
}

// ---------------- host-side GEMM dispatch ----------------
static void gemm(hipStream_t st, const float* A, const float* W, const float* bias,
                 const float* bscale, const float* oscale, float* out,
                 int M, int K, int N, bool gelu, bool res) {
  dim3 g((M + 63) / 64, N / 64), b(256);
  if (gelu)
    gemm_k<true, false><<<g, b, 0, st>>>(A, W, bias, bscale, oscale, out, M, K, N);
  else if (res)
    gemm_k<false, true><<<g, b, 0, st>>>(A, W, bias, bscale, oscale, out, M, K, N);
  else
    gemm_k<false, false><<<g, b, 0, st>>>(A, W, bias, bscale, oscale, out, M, K, N);
}

extern "C" void kernel_launch(void* const* d_in, const int* in_sizes, int n_in,
                              void* d_out, int out_size, void* d_ws, size_t ws_size,
                              hipStream_t stream) {
  (void)in_sizes; (void)n_in; (void)out_size; (void)ws_size;
  const float* query = (const float*)d_in[0];
  const float* ref_points = (const float*)d_in[1];
  const float* ref3d = (const float*)d_in[2];
  const float* imgf = (const float*)d_in[3];
  const unsigned char* maskp = (const unsigned char*)d_in[4];
  const int* x_idx = (const int*)d_in[5];
  const int* y_idx = (const int*)d_in[6];
  const int* z_idx = (const int*)d_in[7];
  const float* c_ln1_g = (const float*)d_in[8];
  const float* c_ln1_b = (const float*)d_in[9];
  const float* c_dp_w = (const float*)d_in[10];
  const float* c_dp_b = (const float*)d_in[11];
  const float* c_a_w = (const float*)d_in[12];
  const float* c_a_b = (const float*)d_in[13];
  const float* c_w_w = (const float*)d_in[14];
  const float* c_w_b = (const float*)d_in[15];
  const float* c_vp_w = (const float*)d_in[16];
  const float* c_vp_b = (const float*)d_in[17];
  const float* c_op_w = (const float*)d_in[18];
  const float* c_op_b = (const float*)d_in[19];
  const float* c_ln2_g = (const float*)d_in[20];
  const float* c_ln2_b = (const float*)d_in[21];
  const float* c_ff1_w = (const float*)d_in[22];
  const float* c_ff1_b = (const float*)d_in[23];
  const float* c_ff2_w = (const float*)d_in[24];
  const float* c_ff2_b = (const float*)d_in[25];
  const float* s_ln1_g = (const float*)d_in[26];
  const float* s_ln1_b = (const float*)d_in[27];
  const float* s_dp_w = (const float*)d_in[28];
  const float* s_dp_b = (const float*)d_in[29];
  const float* s_a_w = (const float*)d_in[30];
  const float* s_a_b = (const float*)d_in[31];
  const float* s_w_w = (const float*)d_in[32];
  const float* s_w_b = (const float*)d_in[33];
  const float* s_vp_w = (const float*)d_in[34];
  const float* s_vp_b = (const float*)d_in[35];
  const float* s_op_w = (const float*)d_in[36];
  const float* s_op_b = (const float*)d_in[37];
  const float* s_ln2_g = (const float*)d_in[38];
  const float* s_ln2_b = (const float*)d_in[39];
  const float* s_ff1_w = (const float*)d_in[40];
  const float* s_ff1_b = (const float*)d_in[41];
  const float* s_ff2_w = (const float*)d_in[42];
  const float* s_ff2_b = (const float*)d_in[43];
  const float* cls_w = (const float*)d_in[44];
  const float* cls_b = (const float*)d_in[45];
  float* out = (float*)d_out;

  char* ws = (char*)d_ws;
  size_t off = 0;
  auto carve = [&](size_t bytes) -> char* {
    char* p = ws + off;
    off += (bytes + 255) & ~(size_t)255;
    return p;
  };
  int* flag = (int*)carve(256);
  float* mcnt = (float*)carve(BQ * 4);
  float* invden = (float*)carve(BQ * 4);
  float* many = (float*)carve(BQ * 4);
  float* dpg = (float*)carve((size_t)BQ * 24 * 4);   // cross dp (stride 16) / self coords (stride 24)
  float* attb = (float*)carve((size_t)BQ * 8 * 4);
  float* Rb = (float*)carve((size_t)BQ * 128 * 4);
  float* Avec = (float*)carve(BQ * 4);
  float* t1 = (float*)carve((size_t)BQ * 128 * 4);
  float* sb = (float*)carve((size_t)BQ * 128 * 4);
  float* qln = (float*)carve((size_t)BQ * 128 * 4);
  float* qb = (float*)carve((size_t)BQ * 128 * 4);
  float* hb = (float*)carve((size_t)BQ * DFF * 4);
  int* winner = (int*)carve((size_t)BB * VYC * VXC * VZC * 4);
  // imgT (9.46MB, cross phase) and vol (16.78MB, self phase) share one region
  float* volimg = (float*)carve((size_t)BB * VYC * VXC * VZC * 128 * 4);
  float* imgT = volimg;
  float* vol = volimg;

  const size_t volbytes = (size_t)BB * VYC * VXC * VZC * 128 * 4;
  const int M = BQ;

  detect_mask_k<<<1, 256, 0, stream>>>(maskp, flag);
  precompute_k<<<(BQ + 255) / 256, 256, 0, stream>>>(maskp, flag, mcnt, invden, many);
  {
    const int total = BB * NCAM * D_MODELC * HFI * WFI;
    transpose_img_k<<<(total + 255) / 256, 256, 0, stream>>>(imgf, imgT);
  }
  hipMemcpyAsync(qb, query, (size_t)BQ * 128 * 4, hipMemcpyDeviceToDevice, stream);

  // ---------------- cross attention stack ----------------
  for (int i = 0; i < NCROSS; ++i) {
    ln_proj_cross_k<<<BQ, 128, 0, stream>>>(qb, c_ln1_g + i * 128, c_ln1_b + i * 128,
                                            c_dp_w + (size_t)i * 128 * 16, c_dp_b + i * 16,
                                            c_a_w + (size_t)i * 128 * 8, c_a_b + i * 8,
                                            dpg, attb);
    cross_sample_k<<<BQ, 128, 0, stream>>>(imgT, ref_points, dpg, attb, maskp, flag, Rb, Avec);
    gemm(stream, Rb, c_vp_w + (size_t)i * 128 * 128, c_vp_b + i * 128, Avec, nullptr, t1,
         M, 128, 128, false, false);
    gemm(stream, t1, c_w_w + (size_t)i * 128 * 128, c_w_b + i * 128, mcnt, invden, sb,
         M, 128, 128, false, false);
    gemm(stream, sb, c_op_w + (size_t)i * 128 * 128, c_op_b + i * 128, nullptr, nullptr, qb,
         M, 128, 128, false, true);
    ln_k<<<BQ, 128, 0, stream>>>(qb, c_ln2_g + i * 128, c_ln2_b + i * 128, qln);
    gemm(stream, qln, c_ff1_w + (size_t)i * 128 * DFF, c_ff1_b + i * DFF, nullptr, nullptr, hb,
         M, 128, DFF, true, false);
    gemm(stream, hb, c_ff2_w + (size_t)i * DFF * 128, c_ff2_b + i * 128, nullptr, nullptr, qb,
         M, DFF, 128, false, true);
  }

  // ---------------- self attention stack ----------------
  for (int i = 0; i < NSELF; ++i) {
    hipMemsetAsync(vol, 0, volbytes, stream);
    hipMemsetAsync(winner, 0xFF, (size_t)BB * VYC * VXC * VZC * 4, stream);
    scatter_winner_k<<<(BQ + 255) / 256, 256, 0, stream>>>(x_idx, y_idx, z_idx, winner);
    scatter_write_k<<<(BQ * 128 + 255) / 256, 256, 0, stream>>>(x_idx, y_idx, z_idx, winner, qb, vol);
    ln_proj_self_k<<<BQ, 128, 0, stream>>>(qb, ref3d, s_ln1_g + i * 128, s_ln1_b + i * 128,
                                           s_dp_w + (size_t)i * 128 * 24, s_dp_b + i * 24,
                                           s_a_w + (size_t)i * 128 * 8, s_a_b + i * 8,
                                           dpg, attb);
    self_sample_k<<<BQ, 128, 0, stream>>>(vol, dpg, attb, Rb);
    gemm(stream, Rb, s_vp_w + (size_t)i * 128 * 128, s_vp_b + i * 128, nullptr, nullptr, t1,
         M, 128, 128, false, false);
    gemm(stream, t1, s_w_w + (size_t)i * 128 * 128, s_w_b + i * 128, nullptr, many, sb,
         M, 128, 128, false, false);
    gemm(stream, sb, s_op_w + (size_t)i * 128 * 128, s_op_b + i * 128, nullptr, nullptr, qb,
         M, 128, 128, false, true);
    ln_k<<<BQ, 128, 0, stream>>>(qb, s_ln2_g + i * 128, s_ln2_b + i * 128, qln);
    gemm(stream, qln, s_ff1_w + (size_t)i * 128 * DFF, s_ff1_b + i * DFF, nullptr, nullptr, hb,
         M, 128, DFF, true, false);
    gemm(stream, hb, s_ff2_w + (size_t)i * DFF * 128, s_ff2_b + i * 128, nullptr, nullptr, qb,
         M, DFF, 128, false, true);
  }

  classifier_k<<<BQ, 128, 0, stream>>>(qb, cls_w, cls_b, out);
}

// Round 2
// 546.293 us; speedup vs baseline: 1.5966x; 1.5966x over previous
//
#include <hip/hip_runtime.h>
#include <math.h>

#define D_MODELC 128
#define NSAMP 8
#define DFF 512
#define NCROSS 3
#define NSELF 2
#define PREDN 4
#define BB 2
#define NCAM 5
#define QQ 2500
#define HFI 24
#define WFI 77
#define VXC 32
#define VYC 16
#define VZC 32
#define BQ (BB*QQ)
#define HWI (HFI*WFI)
#define NVOX (VYC*VXC*VZC)

typedef float f4 __attribute__((ext_vector_type(4)));
typedef short s8v __attribute__((ext_vector_type(8)));

__device__ __forceinline__ unsigned short f2bf(float f) {
  union { float f; unsigned u; } v; v.f = f;
  unsigned r = v.u + 0x7FFFu + ((v.u >> 16) & 1u);
  return (unsigned short)(r >> 16);
}
__device__ __forceinline__ float bf2f(unsigned short u) {
  union { unsigned u; float f; } v; v.u = ((unsigned)u) << 16; return v.f;
}

__device__ __forceinline__ float blocksum128(float v, float* red2) {
#pragma unroll
  for (int off = 32; off > 0; off >>= 1) v += __shfl_down(v, off);
  int lane = threadIdx.x & 63;
  int w = threadIdx.x >> 6;
  if (lane == 0) red2[w] = v;
  __syncthreads();
  float r = red2[0] + red2[1];
  __syncthreads();
  return r;
}

// ---------------- mask dtype detection ----------------
__global__ void detect_mask_k(const unsigned char* __restrict__ m, int* __restrict__ flag) {
  __shared__ int f;
  if (threadIdx.x == 0) f = 0;
  __syncthreads();
  const int total = BB * NCAM * QQ;
  for (int i = threadIdx.x; i < total; i += blockDim.x)
    if ((i & 3) && m[i]) f = 1;
  __syncthreads();
  if (threadIdx.x == 0) *flag = f;
}

__device__ __forceinline__ bool mask_at(const unsigned char* m, const int* flag, int idx) {
  if (*flag) return m[idx] != 0;
  return ((const int*)m)[idx] != 0;
}

// ---------------- per-(b,q) mask stats ----------------
__global__ void precompute_k(const unsigned char* __restrict__ maskp, const int* __restrict__ flag,
                             float* __restrict__ invden, float* __restrict__ imc,
                             float* __restrict__ many) {
  int i = blockIdx.x * blockDim.x + threadIdx.x;
  if (i >= BQ) return;
  int b = i / QQ, q = i % QQ;
  float cnt = 0.f;
  for (int n = 0; n < NCAM; ++n)
    cnt += mask_at(maskp, flag, (b * NCAM + n) * QQ + q) ? 1.f : 0.f;
  float inv = 1.f / (cnt + 1e-6f);
  invden[i] = inv;
  imc[i] = cnt * inv;
  many[i] = cnt > 0.f ? 1.f : 0.f;
}

// ---------------- image transpose [BN,C,H,W] f32 -> [BN,H,W,C] bf16 (LDS tile) ----------------
__global__ __launch_bounds__(256) void transpose_img_k(const float* __restrict__ in,
                                                       unsigned short* __restrict__ out) {
  __shared__ float til[32][65];
  int bn = blockIdx.z;
  int c0 = blockIdx.y * 32;
  int yx0 = blockIdx.x * 64;
  int t = threadIdx.x;
  {
    int yx_l = t & 63, c_l = t >> 6;  // c_l 0..3
    int yx = yx0 + yx_l;
#pragma unroll
    for (int i = 0; i < 8; ++i) {
      int c = c_l + 4 * i;  // 0..31
      float v = 0.f;
      if (yx < HWI) v = in[((size_t)(bn * D_MODELC + c0 + c)) * HWI + yx];
      til[c][yx_l] = v;
    }
  }
  __syncthreads();
  {
    int yx_l = t >> 2, cc = (t & 3) * 8;
    int yx = yx0 + yx_l;
    if (yx < HWI) {
      union { unsigned short u[8]; s8v v; } pk;
#pragma unroll
      for (int j = 0; j < 8; ++j) pk.u[j] = f2bf(til[cc + j][yx_l]);
      *(s8v*)(out + ((size_t)bn * HWI + yx) * D_MODELC + c0 + cc) = pk.v;
    }
  }
}

// ---------------- fused LN + small projections (cross) ----------------
__global__ void ln_proj_cross_k(const float* __restrict__ qb,
                                const float* __restrict__ g, const float* __restrict__ bb,
                                const float* __restrict__ dpw, const float* __restrict__ dpb,
                                const float* __restrict__ aw, const float* __restrict__ ab,
                                float* __restrict__ dp_out, float* __restrict__ att_out) {
  __shared__ float red2[2];
  __shared__ float sln[128];
  __shared__ float part[4][32];
  __shared__ float attv[8];
  int row = blockIdx.x, t = threadIdx.x;
  float x = qb[row * 128 + t];
  float mu = blocksum128(x, red2) * (1.f / 128.f);
  float d = x - mu;
  float var = blocksum128(d * d, red2) * (1.f / 128.f);
  sln[t] = d * rsqrtf(var + 1e-5f) * g[t] + bb[t];
  __syncthreads();
  int col = t & 31, grp = t >> 5;
  float p = 0.f;
  if (col < 24) {
    int k0 = grp * 32;
    for (int k = k0; k < k0 + 32; ++k) {
      float w = (col < 16) ? dpw[k * 16 + col] : aw[k * 8 + (col - 16)];
      p += sln[k] * w;
    }
  }
  part[grp][col] = p;
  __syncthreads();
  if (t < 24) {
    float v = part[0][t] + part[1][t] + part[2][t] + part[3][t];
    if (t < 16) dp_out[row * 16 + t] = v + dpb[t];
    else attv[t - 16] = v + ab[t - 16];
  }
  __syncthreads();
  if (t == 0) {
    float mx = attv[0];
#pragma unroll
    for (int i = 1; i < 8; ++i) mx = fmaxf(mx, attv[i]);
    float e[8], s = 0.f;
#pragma unroll
    for (int i = 0; i < 8; ++i) { e[i] = expf(attv[i] - mx); s += e[i]; }
    float inv = 1.f / s;
#pragma unroll
    for (int i = 0; i < 8; ++i) att_out[row * 8 + i] = e[i] * inv;
  }
}

// ---------------- fused LN + small projections (self) ----------------
__global__ void ln_proj_self_k(const float* __restrict__ qb, const float* __restrict__ ref3d,
                               const float* __restrict__ g, const float* __restrict__ bb,
                               const float* __restrict__ dpw, const float* __restrict__ dpb,
                               const float* __restrict__ aw, const float* __restrict__ ab,
                               float* __restrict__ g_out, float* __restrict__ att_out) {
  __shared__ float red2[2];
  __shared__ float sln[128];
  __shared__ float part[4][32];
  __shared__ float attv[8];
  __shared__ float dpl[24];
  int row = blockIdx.x, t = threadIdx.x;
  float x = qb[row * 128 + t];
  float mu = blocksum128(x, red2) * (1.f / 128.f);
  float d = x - mu;
  float var = blocksum128(d * d, red2) * (1.f / 128.f);
  sln[t] = d * rsqrtf(var + 1e-5f) * g[t] + bb[t];
  __syncthreads();
  int col = t & 31, grp = t >> 5;
  float p = 0.f;
  {
    int k0 = grp * 32;
    for (int k = k0; k < k0 + 32; ++k) {
      float w = (col < 24) ? dpw[k * 24 + col] : aw[k * 8 + (col - 24)];
      p += sln[k] * w;
    }
  }
  part[grp][col] = p;
  __syncthreads();
  if (t < 32) {
    float v = part[0][t] + part[1][t] + part[2][t] + part[3][t];
    if (t < 24) dpl[t] = v + dpb[t];
    else attv[t - 24] = v + ab[t - 24];
  }
  __syncthreads();
  if (t == 0) {
    float mx = attv[0];
#pragma unroll
    for (int i = 1; i < 8; ++i) mx = fmaxf(mx, attv[i]);
    float e[8], s = 0.f;
#pragma unroll
    for (int i = 0; i < 8; ++i) { e[i] = expf(attv[i] - mx); s += e[i]; }
    float inv = 1.f / s;
#pragma unroll
    for (int i = 0; i < 8; ++i) att_out[row * 8 + i] = e[i] * inv;
  }
  if (t < 24) {
    int s_ = t / 3, j = t % 3;
    int pc = (j == 0) ? 1 : ((j == 1) ? 0 : 2);  // perm [1,0,2]
    g_out[row * 24 + t] = ref3d[row * 3 + pc] + dpl[s_ * 3 + pc];
  }
}

// ---------------- cross deformable sampling (bf16 img, 32 lanes/query) ----------------
__global__ __launch_bounds__(256) void cross_sample_k(const unsigned short* __restrict__ imgT,
                                                      const float* __restrict__ refp,
                                                      const float* __restrict__ dp,
                                                      const float* __restrict__ att,
                                                      const unsigned char* __restrict__ maskp,
                                                      const int* __restrict__ flag,
                                                      float* __restrict__ R, float* __restrict__ Avec) {
  __shared__ __align__(16) int soff[320][4];
  __shared__ __align__(16) float sw[320][4];
  int t = threadIdx.x, blk = blockIdx.x;
  for (int e = t; e < 320; e += 256) {
    int qi = e / 40, rem = e % 40;
    int n = rem >> 3, s = rem & 7;
    int row = blk * 8 + qi;
    int b = row / QQ, q = row - b * QQ;
    int mi = (b * NCAM + n) * QQ + q;
    bool mk = mask_at(maskp, flag, mi);
    float a = mk ? att[row * 8 + s] : 0.f;
    float rx = refp[(size_t)mi * 2 + 0];
    float ry = refp[(size_t)mi * 2 + 1];
    float fx = (rx + dp[row * 16 + s * 2 + 0]) * (float)(WFI - 1);
    float fy = (ry + dp[row * 16 + s * 2 + 1]) * (float)(HFI - 1);
    float x0f = floorf(fx), y0f = floorf(fy);
    int x0 = (int)x0f, y0 = (int)y0f;
    float xd = fx - x0f, yd = fy - y0f;
    int base = (b * NCAM + n) * HWI;
#pragma unroll
    for (int cy = 0; cy < 2; ++cy)
#pragma unroll
      for (int cx = 0; cx < 2; ++cx) {
        int xi = x0 + cx, yi = y0 + cy;
        bool ok = (xi >= 0) & (xi < WFI) & (yi >= 0) & (yi < HFI);
        int xc = min(max(xi, 0), WFI - 1), yc = min(max(yi, 0), HFI - 1);
        soff[e][cy * 2 + cx] = (base + yc * WFI + xc) * 128;
        sw[e][cy * 2 + cx] = ok ? a * (cx ? xd : 1.f - xd) * (cy ? yd : 1.f - yd) : 0.f;
      }
  }
  __syncthreads();
  int qi = t >> 5, ln = t & 31;
  float acc0 = 0.f, acc1 = 0.f, acc2 = 0.f, acc3 = 0.f, wa = 0.f;
  for (int e = 0; e < 40; ++e) {
    int eb = qi * 40 + e;
    float4 wv = *(const float4*)&sw[eb][0];
    float wsum = wv.x + wv.y + wv.z + wv.w;
    if (wsum != 0.f) {
      int4 ov = *(const int4*)&soff[eb][0];
      ushort4 p0 = *(const ushort4*)(imgT + (size_t)ov.x + ln * 4);
      ushort4 p1 = *(const ushort4*)(imgT + (size_t)ov.y + ln * 4);
      ushort4 p2 = *(const ushort4*)(imgT + (size_t)ov.z + ln * 4);
      ushort4 p3 = *(const ushort4*)(imgT + (size_t)ov.w + ln * 4);
      acc0 += wv.x * bf2f(p0.x) + wv.y * bf2f(p1.x) + wv.z * bf2f(p2.x) + wv.w * bf2f(p3.x);
      acc1 += wv.x * bf2f(p0.y) + wv.y * bf2f(p1.y) + wv.z * bf2f(p2.y) + wv.w * bf2f(p3.y);
      acc2 += wv.x * bf2f(p0.z) + wv.y * bf2f(p1.z) + wv.z * bf2f(p2.z) + wv.w * bf2f(p3.z);
      acc3 += wv.x * bf2f(p0.w) + wv.y * bf2f(p1.w) + wv.z * bf2f(p2.w) + wv.w * bf2f(p3.w);
      wa += wsum;
    }
  }
  int row = blk * 8 + qi;
  float4 r; r.x = acc0; r.y = acc1; r.z = acc2; r.w = acc3;
  *(float4*)(R + (size_t)row * 128 + ln * 4) = r;
  if (ln == 0) Avec[row] = wa;
}

// ---------------- voxel scatter ----------------
__global__ void scatter_winner_k(const int* __restrict__ xi, const int* __restrict__ yi,
                                 const int* __restrict__ zi, int* __restrict__ winner) {
  int i = blockIdx.x * blockDim.x + threadIdx.x;
  if (i >= BQ) return;
  int b = i / QQ;
  int vox = yi[i] * (VXC * VZC) + xi[i] * VZC + zi[i];
  atomicMax(&winner[b * NVOX + vox], i % QQ);
}

__global__ void scatter_write_k(const int* __restrict__ xi, const int* __restrict__ yi,
                                const int* __restrict__ zi, const int* __restrict__ winner,
                                const float* __restrict__ qb, unsigned short* __restrict__ vol) {
  int idx = blockIdx.x * blockDim.x + threadIdx.x;
  if (idx >= BQ * 16) return;
  int g = idx & 15, row = idx >> 4;
  int b = row / QQ, q = row % QQ;
  int vox = yi[row] * (VXC * VZC) + xi[row] * VZC + zi[row];
  if (winner[b * NVOX + vox] != q) return;
  const float* src = qb + (size_t)row * 128 + g * 8;
  float4 a = *(const float4*)src;
  float4 c = *(const float4*)(src + 4);
  union { unsigned short u[8]; s8v v; } pk;
  pk.u[0] = f2bf(a.x); pk.u[1] = f2bf(a.y); pk.u[2] = f2bf(a.z); pk.u[3] = f2bf(a.w);
  pk.u[4] = f2bf(c.x); pk.u[5] = f2bf(c.y); pk.u[6] = f2bf(c.z); pk.u[7] = f2bf(c.w);
  *(s8v*)(vol + ((size_t)b * NVOX + vox) * 128 + g * 8) = pk.v;
}

// ---------------- 3d deformable sampling (bf16 vol, 32 lanes/query) ----------------
__global__ __launch_bounds__(256) void self_sample_k(const unsigned short* __restrict__ vol,
                                                     const float* __restrict__ gc,
                                                     const float* __restrict__ att,
                                                     float* __restrict__ R3) {
  __shared__ __align__(16) int soff[64][8];
  __shared__ __align__(16) float sw[64][8];
  int t = threadIdx.x, blk = blockIdx.x;
  if (t < 64) {
    int qi = t >> 3, s = t & 7;
    int row = blk * 8 + qi;
    int b = row / QQ;
    float a = att[row * 8 + s];
    float fx = (gc[row * 24 + s * 3 + 0] + 1.f) * 0.5f * (float)(VZC - 1);
    float fy = (gc[row * 24 + s * 3 + 1] + 1.f) * 0.5f * (float)(VXC - 1);
    float fz = (gc[row * 24 + s * 3 + 2] + 1.f) * 0.5f * (float)(VYC - 1);
    float x0f = floorf(fx), y0f = floorf(fy), z0f = floorf(fz);
    int x0 = (int)x0f, y0 = (int)y0f, z0 = (int)z0f;
    float xd = fx - x0f, yd = fy - y0f, zd = fz - z0f;
    int base = b * NVOX;
#pragma unroll
    for (int cz = 0; cz < 2; ++cz)
#pragma unroll
      for (int cy = 0; cy < 2; ++cy)
#pragma unroll
        for (int cx = 0; cx < 2; ++cx) {
          int xi = x0 + cx, yi = y0 + cy, zi = z0 + cz;
          bool ok = (xi >= 0) & (xi < VZC) & (yi >= 0) & (yi < VXC) & (zi >= 0) & (zi < VYC);
          int xc = min(max(xi, 0), VZC - 1);
          int yc = min(max(yi, 0), VXC - 1);
          int zc = min(max(zi, 0), VYC - 1);
          int ci = cz * 4 + cy * 2 + cx;
          soff[t][ci] = (base + (zc * VXC + yc) * VZC + xc) * 128;
          sw[t][ci] = ok ? a * (cx ? xd : 1.f - xd) * (cy ? yd : 1.f - yd) * (cz ? zd : 1.f - zd) : 0.f;
        }
  }
  __syncthreads();
  int qi = t >> 5, ln = t & 31;
  float acc0 = 0.f, acc1 = 0.f, acc2 = 0.f, acc3 = 0.f;
  for (int e = 0; e < 8; ++e) {
    int eb = qi * 8 + e;
#pragma unroll
    for (int c = 0; c < 8; ++c) {
      float w = sw[eb][c];
      if (w != 0.f) {
        ushort4 p = *(const ushort4*)(vol + (size_t)soff[eb][c] + ln * 4);
        acc0 += w * bf2f(p.x);
        acc1 += w * bf2f(p.y);
        acc2 += w * bf2f(p.z);
        acc3 += w * bf2f(p.w);
      }
    }
  }
  int row = blk * 8 + qi;
  float4 r; r.x = acc0; r.y = acc1; r.z = acc2; r.w = acc3;
  *(float4*)(R3 + (size_t)row * 128 + ln * 4) = r;
}

// ---------------- small f32 128x128x128 batched GEMM (weight precompute) ----------------
struct P5 { const float* a[5]; const float* b[5]; float* c[5]; };

__global__ __launch_bounds__(256) void small_mm_k(P5 ps) {
  const float* A = ps.a[blockIdx.z];
  const float* Bm = ps.b[blockIdx.z];
  float* C = ps.c[blockIdx.z];
  __shared__ float As_[32][64];
  __shared__ float Ws_[32][64];
  int m0 = blockIdx.x * 64, n0 = blockIdx.y * 64, tid = threadIdx.x;
  float acc[4][4] = {};
  int mr = (tid >> 4) * 4, nc = (tid & 15) * 4;
  for (int k0 = 0; k0 < 128; k0 += 32) {
    {
      int r = tid >> 2, kq = (tid & 3) * 8;
      const float* ap = A + (size_t)(m0 + r) * 128 + k0 + kq;
      float4 v0 = *(const float4*)ap, v1 = *(const float4*)(ap + 4);
      As_[kq + 0][r] = v0.x; As_[kq + 1][r] = v0.y; As_[kq + 2][r] = v0.z; As_[kq + 3][r] = v0.w;
      As_[kq + 4][r] = v1.x; As_[kq + 5][r] = v1.y; As_[kq + 6][r] = v1.z; As_[kq + 7][r] = v1.w;
    }
    {
      int kr = tid >> 3, nq = (tid & 7) * 8;
      const float* wp = Bm + (size_t)(k0 + kr) * 128 + n0 + nq;
      *(float4*)&Ws_[kr][nq] = *(const float4*)wp;
      *(float4*)&Ws_[kr][nq + 4] = *(const float4*)(wp + 4);
    }
    __syncthreads();
#pragma unroll
    for (int kk = 0; kk < 32; ++kk) {
      float4 av = *(const float4*)&As_[kk][mr];
      float4 bv = *(const float4*)&Ws_[kk][nc];
      float a_[4] = {av.x, av.y, av.z, av.w};
      float b_[4] = {bv.x, bv.y, bv.z, bv.w};
#pragma unroll
      for (int i = 0; i < 4; ++i)
#pragma unroll
        for (int j = 0; j < 4; ++j) acc[i][j] += a_[i] * b_[j];
    }
    __syncthreads();
  }
#pragma unroll
  for (int i = 0; i < 4; ++i) {
    float4 r;
    r.x = acc[i][0]; r.y = acc[i][1]; r.z = acc[i][2]; r.w = acc[i][3];
    *(float4*)(C + (size_t)(m0 + mr + i) * 128 + n0 + nc) = r;
  }
}

// ---------------- per-layer constant vectors ----------------
__global__ void pre_vec_k(const float* __restrict__ c_vp_b, const float* __restrict__ c_w_b,
                          const float* __restrict__ s_vp_b, const float* __restrict__ s_w_b,
                          const float* __restrict__ c_op_w, const float* __restrict__ s_op_w,
                          const float* __restrict__ Qbuf,
                          float* __restrict__ v1buf, float* __restrict__ v2buf,
                          float* __restrict__ csbuf) {
  int L = blockIdx.x, n = threadIdx.x;
  const float* vpb = L < 3 ? c_vp_b + L * 128 : s_vp_b + (L - 3) * 128;
  const float* wb = L < 3 ? c_w_b + L * 128 : s_w_b + (L - 3) * 128;
  const float* op = L < 3 ? c_op_w + (size_t)L * 16384 : s_op_w + (size_t)(L - 3) * 16384;
  const float* Q = Qbuf + (size_t)L * 16384;
  float a = 0.f, c = 0.f;
  for (int k = 0; k < 128; ++k) {
    a += vpb[k] * Q[k * 128 + n];
    c += wb[k] * op[k * 128 + n];
  }
  if (L < 3) { v1buf[L * 128 + n] = a; v2buf[L * 128 + n] = c; }
  else csbuf[(L - 3) * 128 + n] = a + c;
}

// ---------------- weight convert+transpose to bf16 [N][K] ----------------
__global__ void wconv_k(const float* __restrict__ Wcbuf,
                        const float* __restrict__ cf1, const float* __restrict__ sf1,
                        const float* __restrict__ cf2, const float* __restrict__ sf2,
                        unsigned short* __restrict__ WcT, unsigned short* __restrict__ f1T,
                        unsigned short* __restrict__ f2T) {
  int widx = blockIdx.y;
  const float* src; unsigned short* dst; int K, N, elems;
  if (widx < 5) { src = Wcbuf + (size_t)widx * 16384; dst = WcT + (size_t)widx * 16384; K = 128; N = 128; elems = 16384; }
  else if (widx < 10) {
    int L = widx - 5;
    src = (L < 3) ? cf1 + (size_t)L * 65536 : sf1 + (size_t)(L - 3) * 65536;
    dst = f1T + (size_t)L * 65536; K = 128; N = 512; elems = 65536;
  } else {
    int L = widx - 10;
    src = (L < 3) ? cf2 + (size_t)L * 65536 : sf2 + (size_t)(L - 3) * 65536;
    dst = f2T + (size_t)L * 65536; K = 512; N = 128; elems = 65536;
  }
  int e = (blockIdx.x * 256 + threadIdx.x) * 4;
  if (e >= elems) return;
  int k = e % K, n = e / K;
  ushort4 o;
  o.x = f2bf(src[(size_t)(k + 0) * N + n]);
  o.y = f2bf(src[(size_t)(k + 1) * N + n]);
  o.z = f2bf(src[(size_t)(k + 2) * N + n]);
  o.w = f2bf(src[(size_t)(k + 3) * N + n]);
  *(ushort4*)(dst + e) = o;
}

// ---------------- MFMA bf16 GEMM: 16 rows/block, 128 cols/block ----------------
// out[m, n] = [res +] act( acc[m,n]*s0[m] + e1a[m]*e1b[m]*v1[n] + e2[m]*v2[n] + bias[n] )
template <int K, bool LNA, bool ABF, bool GELU, bool RES, bool EPI, bool OBF>
__global__ __launch_bounds__(256) void mm_k(const void* __restrict__ Ap,
                                            const unsigned short* __restrict__ WT,
                                            const float* __restrict__ bias,
                                            const float* __restrict__ lng, const float* __restrict__ lnb,
                                            const float* __restrict__ s0, const float* __restrict__ e1a,
                                            const float* __restrict__ e1b, const float* __restrict__ v1,
                                            const float* __restrict__ e2, const float* __restrict__ v2,
                                            void* __restrict__ outp, int M, int Nfull) {
  __shared__ __align__(16) unsigned short As[16 * K];
  int t = threadIdx.x;
  int m0 = blockIdx.x * 16;
  int ncol0 = blockIdx.y * 128;
  int r = t >> 4, cg = t & 15;
  int gm = m0 + r;
  if (ABF) {
    const unsigned short* A = (const unsigned short*)Ap;
#pragma unroll
    for (int i = 0; i < K / 128; ++i) {
      int c0 = cg * (K / 16) + i * 8;
      s8v v = {};
      if (gm < M) v = *(const s8v*)(A + (size_t)gm * K + c0);
      int chunk = (c0 >> 3) ^ (r & 7);
      *(s8v*)&As[r * K + chunk * 8] = v;
    }
  } else {
    const float* A = (const float*)Ap;
    float rv[K / 16];
#pragma unroll
    for (int i = 0; i < K / 16; i += 4) {
      float4 v = make_float4(0.f, 0.f, 0.f, 0.f);
      if (gm < M) v = *(const float4*)(A + (size_t)gm * K + cg * (K / 16) + i);
      rv[i] = v.x; rv[i + 1] = v.y; rv[i + 2] = v.z; rv[i + 3] = v.w;
    }
    if (LNA) {
      float s1 = 0.f, s2 = 0.f;
#pragma unroll
      for (int i = 0; i < K / 16; ++i) { s1 += rv[i]; s2 += rv[i] * rv[i]; }
#pragma unroll
      for (int msk = 1; msk < 16; msk <<= 1) {
        s1 += __shfl_xor(s1, msk);
        s2 += __shfl_xor(s2, msk);
      }
      float mean = s1 * (1.f / K);
      float var = s2 * (1.f / K) - mean * mean;
      float inv = rsqrtf(var + 1e-5f);
#pragma unroll
      for (int i = 0; i < K / 16; ++i) {
        int c = cg * (K / 16) + i;
        rv[i] = (rv[i] - mean) * inv * lng[c] + lnb[c];
      }
    }
#pragma unroll
    for (int i0 = 0; i0 < K / 16; i0 += 8) {
      union { unsigned short u[8]; s8v v; } pk;
#pragma unroll
      for (int j = 0; j < 8; ++j) pk.u[j] = f2bf(rv[i0 + j]);
      int chunk = ((cg * (K / 16) + i0) >> 3) ^ (r & 7);
      *(s8v*)&As[r * K + chunk * 8] = pk.v;
    }
  }
  __syncthreads();
  int w = t >> 6, l = t & 63;
  int la = l & 15, lb = l >> 4;
  int nbase = w * 32;
  f4 acc[2] = {};
#pragma unroll
  for (int ks = 0; ks < K / 32; ++ks) {
    int chunk = ks * 4 + lb;
    s8v af = *(const s8v*)&As[la * K + ((chunk ^ (la & 7))) * 8];
#pragma unroll
    for (int nt = 0; nt < 2; ++nt) {
      int col = ncol0 + nbase + nt * 16 + la;
      s8v bf = *(const s8v*)(WT + (size_t)col * K + ks * 32 + lb * 8);
      acc[nt] = __builtin_amdgcn_mfma_f32_16x16x32_bf16(af, bf, acc[nt], 0, 0, 0);
    }
  }
#pragma unroll
  for (int j = 0; j < 4; ++j) {
    int m = m0 + lb * 4 + j;
    if (m >= M) continue;
    float s0m = 1.f, e1m = 0.f, e2m = 0.f;
    if (EPI) {
      if (s0) s0m = s0[m];
      if (e1a) e1m = e1a[m] * (e1b ? e1b[m] : 1.f);
      if (e2) e2m = e2[m];
    }
#pragma unroll
    for (int nt = 0; nt < 2; ++nt) {
      int col = ncol0 + nbase + nt * 16 + la;
      float val = acc[nt][j];
      if (EPI) val = val * s0m + e1m * v1[col] + (e2 ? e2m * v2[col] : 0.f);
      val += bias[col];
      if (GELU) val = 0.5f * val * (1.f + erff(val * 0.70710678118654752f));
      size_t oi = (size_t)m * Nfull + col;
      if (OBF) ((unsigned short*)outp)[oi] = f2bf(val);
      else {
        float* o = (float*)outp;
        float rr = val;
        if (RES) rr += o[oi];
        o[oi] = rr;
      }
    }
  }
}

// ---------------- classifier ----------------
__global__ void classifier_k(const float* __restrict__ qb, const float* __restrict__ cw,
                             const float* __restrict__ cb, float* __restrict__ out) {
  __shared__ float red[2][4];
  int row = blockIdx.x, t = threadIdx.x;
  float v = qb[row * 128 + t];
  float p0 = v * cw[t * 4 + 0];
  float p1 = v * cw[t * 4 + 1];
  float p2 = v * cw[t * 4 + 2];
  float p3 = v * cw[t * 4 + 3];
#pragma unroll
  for (int off = 32; off > 0; off >>= 1) {
    p0 += __shfl_down(p0, off);
    p1 += __shfl_down(p1, off);
    p2 += __shfl_down(p2, off);
    p3 += __shfl_down(p3, off);
  }
  int lane = t & 63, w = t >> 6;
  if (lane == 0) { red[w][0] = p0; red[w][1] = p1; red[w][2] = p2; red[w][3] = p3; }
  __syncthreads();
  if (t < 4) out[row * 4 + t] = red[0][t] + red[1][t] + cb[t];
}

extern "C" void kernel_launch(void* const* d_in, const int* in_sizes, int n_in,
                              void* d_out, int out_size, void* d_ws, size_t ws_size,
                              hipStream_t stream) {
  (void)in_sizes; (void)n_in; (void)out_size; (void)ws_size;
  const float* query = (const float*)d_in[0];
  const float* ref_points = (const float*)d_in[1];
  const float* ref3d = (const float*)d_in[2];
  const float* imgf = (const float*)d_in[3];
  const unsigned char* maskp = (const unsigned char*)d_in[4];
  const int* x_idx = (const int*)d_in[5];
  const int* y_idx = (const int*)d_in[6];
  const int* z_idx = (const int*)d_in[7];
  const float* c_ln1_g = (const float*)d_in[8];
  const float* c_ln1_b = (const float*)d_in[9];
  const float* c_dp_w = (const float*)d_in[10];
  const float* c_dp_b = (const float*)d_in[11];
  const float* c_a_w = (const float*)d_in[12];
  const float* c_a_b = (const float*)d_in[13];
  const float* c_w_w = (const float*)d_in[14];
  const float* c_w_b = (const float*)d_in[15];
  const float* c_vp_w = (const float*)d_in[16];
  const float* c_vp_b = (const float*)d_in[17];
  const float* c_op_w = (const float*)d_in[18];
  const float* c_op_b = (const float*)d_in[19];
  const float* c_ln2_g = (const float*)d_in[20];
  const float* c_ln2_b = (const float*)d_in[21];
  const float* c_ff1_w = (const float*)d_in[22];
  const float* c_ff1_b = (const float*)d_in[23];
  const float* c_ff2_w = (const float*)d_in[24];
  const float* c_ff2_b = (const float*)d_in[25];
  const float* s_ln1_g = (const float*)d_in[26];
  const float* s_ln1_b = (const float*)d_in[27];
  const float* s_dp_w = (const float*)d_in[28];
  const float* s_dp_b = (const float*)d_in[29];
  const float* s_a_w = (const float*)d_in[30];
  const float* s_a_b = (const float*)d_in[31];
  const float* s_w_w = (const float*)d_in[32];
  const float* s_w_b = (const float*)d_in[33];
  const float* s_vp_w = (const float*)d_in[34];
  const float* s_vp_b = (const float*)d_in[35];
  const float* s_op_w = (const float*)d_in[36];
  const float* s_op_b = (const float*)d_in[37];
  const float* s_ln2_g = (const float*)d_in[38];
  const float* s_ln2_b = (const float*)d_in[39];
  const float* s_ff1_w = (const float*)d_in[40];
  const float* s_ff1_b = (const float*)d_in[41];
  const float* s_ff2_w = (const float*)d_in[42];
  const float* s_ff2_b = (const float*)d_in[43];
  const float* cls_w = (const float*)d_in[44];
  const float* cls_b = (const float*)d_in[45];
  float* out = (float*)d_out;

  char* ws = (char*)d_ws;
  size_t off = 0;
  auto carve = [&](size_t bytes) -> char* {
    char* p = ws + off;
    off += (bytes + 255) & ~(size_t)255;
    return p;
  };
  int* flag = (int*)carve(256);
  float* invden = (float*)carve(BQ * 4);
  float* imc = (float*)carve(BQ * 4);
  float* many = (float*)carve(BQ * 4);
  float* dpg = (float*)carve((size_t)BQ * 24 * 4);
  float* attb = (float*)carve((size_t)BQ * 8 * 4);
  float* Rb = (float*)carve((size_t)BQ * 128 * 4);
  float* Avec = (float*)carve(BQ * 4);
  float* qb = (float*)carve((size_t)BQ * 128 * 4);
  unsigned short* hb = (unsigned short*)carve((size_t)BQ * DFF * 2);
  int* winner = (int*)carve((size_t)BB * NVOX * 4);
  float* Qbuf = (float*)carve((size_t)5 * 16384 * 4);
  float* Wcbuf = (float*)carve((size_t)5 * 16384 * 4);
  unsigned short* WcT = (unsigned short*)carve((size_t)5 * 16384 * 2);
  unsigned short* f1T = (unsigned short*)carve((size_t)5 * 65536 * 2);
  unsigned short* f2T = (unsigned short*)carve((size_t)5 * 65536 * 2);
  float* v1buf = (float*)carve(3 * 128 * 4);
  float* v2buf = (float*)carve(3 * 128 * 4);
  float* csbuf = (float*)carve(2 * 128 * 4);
  unsigned short* volimg = (unsigned short*)carve((size_t)BB * NVOX * 128 * 2);
  unsigned short* imgT = volimg;
  unsigned short* vol = volimg;

  const int M = BQ;

  // ---- setup ----
  detect_mask_k<<<1, 256, 0, stream>>>(maskp, flag);
  precompute_k<<<(BQ + 255) / 256, 256, 0, stream>>>(maskp, flag, invden, imc, many);
  transpose_img_k<<<dim3((HWI + 63) / 64, 4, BB * NCAM), 256, 0, stream>>>(imgf, imgT);
  {
    P5 pq, pw;
    for (int L = 0; L < 5; ++L) {
      pq.a[L] = (L < 3) ? c_w_w + (size_t)L * 16384 : s_w_w + (size_t)(L - 3) * 16384;
      pq.b[L] = (L < 3) ? c_op_w + (size_t)L * 16384 : s_op_w + (size_t)(L - 3) * 16384;
      pq.c[L] = Qbuf + (size_t)L * 16384;
      pw.a[L] = (L < 3) ? c_vp_w + (size_t)L * 16384 : s_vp_w + (size_t)(L - 3) * 16384;
      pw.b[L] = Qbuf + (size_t)L * 16384;
      pw.c[L] = Wcbuf + (size_t)L * 16384;
    }
    small_mm_k<<<dim3(2, 2, 5), 256, 0, stream>>>(pq);
    small_mm_k<<<dim3(2, 2, 5), 256, 0, stream>>>(pw);
  }
  pre_vec_k<<<5, 128, 0, stream>>>(c_vp_b, c_w_b, s_vp_b, s_w_b, c_op_w, s_op_w, Qbuf,
                                   v1buf, v2buf, csbuf);
  wconv_k<<<dim3(64, 15), 256, 0, stream>>>(Wcbuf, c_ff1_w, s_ff1_w, c_ff2_w, s_ff2_w,
                                            WcT, f1T, f2T);
  hipMemcpyAsync(qb, query, (size_t)BQ * 128 * 4, hipMemcpyDeviceToDevice, stream);

  const int GB = (M + 15) / 16;  // 313

  // ---- cross attention stack ----
  for (int i = 0; i < NCROSS; ++i) {
    ln_proj_cross_k<<<BQ, 128, 0, stream>>>(qb, c_ln1_g + i * 128, c_ln1_b + i * 128,
                                            c_dp_w + (size_t)i * 128 * 16, c_dp_b + i * 16,
                                            c_a_w + (size_t)i * 128 * 8, c_a_b + i * 8,
                                            dpg, attb);
    cross_sample_k<<<BQ / 8, 256, 0, stream>>>(imgT, ref_points, dpg, attb, maskp, flag, Rb, Avec);
    mm_k<128, false, false, false, true, true, false><<<dim3(GB, 1), 256, 0, stream>>>(
        Rb, WcT + (size_t)i * 16384, c_op_b + i * 128, nullptr, nullptr,
        invden, invden, Avec, v1buf + i * 128, imc, v2buf + i * 128, qb, M, 128);
    mm_k<128, true, false, true, false, false, true><<<dim3(GB, 4), 256, 0, stream>>>(
        qb, f1T + (size_t)i * 65536, c_ff1_b + i * 512, c_ln2_g + i * 128, c_ln2_b + i * 128,
        nullptr, nullptr, nullptr, nullptr, nullptr, nullptr, hb, M, 512);
    mm_k<512, false, true, false, true, false, false><<<dim3(GB, 1), 256, 0, stream>>>(
        hb, f2T + (size_t)i * 65536, c_ff2_b + i * 128, nullptr, nullptr,
        nullptr, nullptr, nullptr, nullptr, nullptr, nullptr, qb, M, 128);
  }

  // ---- self attention stack ----
  for (int i = 0; i < NSELF; ++i) {
    hipMemsetAsync(vol, 0, (size_t)BB * NVOX * 128 * 2, stream);
    hipMemsetAsync(winner, 0xFF, (size_t)BB * NVOX * 4, stream);
    scatter_winner_k<<<(BQ + 255) / 256, 256, 0, stream>>>(x_idx, y_idx, z_idx, winner);
    scatter_write_k<<<(BQ * 16 + 255) / 256, 256, 0, stream>>>(x_idx, y_idx, z_idx, winner, qb, vol);
    ln_proj_self_k<<<BQ, 128, 0, stream>>>(qb, ref3d, s_ln1_g + i * 128, s_ln1_b + i * 128,
                                           s_dp_w + (size_t)i * 128 * 24, s_dp_b + i * 24,
                                           s_a_w + (size_t)i * 128 * 8, s_a_b + i * 8,
                                           dpg, attb);
    self_sample_k<<<BQ / 8, 256, 0, stream>>>(vol, dpg, attb, Rb);
    mm_k<128, false, false, false, true, true, false><<<dim3(GB, 1), 256, 0, stream>>>(
        Rb, WcT + (size_t)(3 + i) * 16384, s_op_b + i * 128, nullptr, nullptr,
        many, many, nullptr, csbuf + i * 128, nullptr, nullptr, qb, M, 128);
    mm_k<128, true, false, true, false, false, true><<<dim3(GB, 4), 256, 0, stream>>>(
        qb, f1T + (size_t)(3 + i) * 65536, s_ff1_b + i * 512, s_ln2_g + i * 128, s_ln2_b + i * 128,
        nullptr, nullptr, nullptr, nullptr, nullptr, nullptr, hb, M, 512);
    mm_k<512, false, true, false, true, false, false><<<dim3(GB, 1), 256, 0, stream>>>(
        hb, f2T + (size_t)(3 + i) * 65536, s_ff2_b + i * 128, nullptr, nullptr,
        nullptr, nullptr, nullptr, nullptr, nullptr, nullptr, qb, M, 128);
  }

  classifier_k<<<BQ, 128, 0, stream>>>(qb, cls_w, cls_b, out);
}

// Round 3
// 535.646 us; speedup vs baseline: 1.6284x; 1.0199x over previous
//
#include <hip/hip_runtime.h>
#include <math.h>

#define D_MODELC 128
#define NSAMP 8
#define DFF 512
#define NCROSS 3
#define NSELF 2
#define BB 2
#define NCAM 5
#define QQ 2500
#define HFI 24
#define WFI 77
#define VXC 32
#define VYC 16
#define VZC 32
#define BQ (BB*QQ)
#define HWI (HFI*WFI)
#define NVOX (VYC*VXC*VZC)

typedef float f4 __attribute__((ext_vector_type(4)));
typedef short s8v __attribute__((ext_vector_type(8)));

__device__ __forceinline__ unsigned short f2bf(float f) {
  union { float f; unsigned u; } v; v.f = f;
  unsigned r = v.u + 0x7FFFu + ((v.u >> 16) & 1u);
  return (unsigned short)(r >> 16);
}
__device__ __forceinline__ float bf2f(unsigned short u) {
  union { unsigned u; float f; } v; v.u = ((unsigned)u) << 16; return v.f;
}

// ---------------- mask dtype detection ----------------
__global__ void detect_mask_k(const unsigned char* __restrict__ m, int* __restrict__ flag) {
  __shared__ int f;
  if (threadIdx.x == 0) f = 0;
  __syncthreads();
  const int total = BB * NCAM * QQ;
  for (int i = threadIdx.x; i < total; i += blockDim.x)
    if ((i & 3) && m[i]) f = 1;
  __syncthreads();
  if (threadIdx.x == 0) *flag = f;
}

__device__ __forceinline__ bool mask_at(const unsigned char* m, const int* flag, int idx) {
  if (*flag) return m[idx] != 0;
  return ((const int*)m)[idx] != 0;
}

// ---------------- per-(b,q) mask stats ----------------
__global__ void precompute_k(const unsigned char* __restrict__ maskp, const int* __restrict__ flag,
                             float* __restrict__ invden, float* __restrict__ imc,
                             float* __restrict__ many) {
  int i = blockIdx.x * blockDim.x + threadIdx.x;
  if (i >= BQ) return;
  int b = i / QQ, q = i % QQ;
  float cnt = 0.f;
  for (int n = 0; n < NCAM; ++n)
    cnt += mask_at(maskp, flag, (b * NCAM + n) * QQ + q) ? 1.f : 0.f;
  float inv = 1.f / (cnt + 1e-6f);
  invden[i] = inv;
  imc[i] = cnt * inv;
  many[i] = cnt > 0.f ? 1.f : 0.f;
}

// ---------------- image transpose [BN,C,H,W] f32 -> [BN,H,W,C] bf16 ----------------
__global__ __launch_bounds__(256) void transpose_img_k(const float* __restrict__ in,
                                                       unsigned short* __restrict__ out) {
  __shared__ float til[32][65];
  int bn = blockIdx.z;
  int c0 = blockIdx.y * 32;
  int yx0 = blockIdx.x * 64;
  int t = threadIdx.x;
  {
    int yx_l = t & 63, c_l = t >> 6;
    int yx = yx0 + yx_l;
#pragma unroll
    for (int i = 0; i < 8; ++i) {
      int c = c_l + 4 * i;
      float v = 0.f;
      if (yx < HWI) v = in[((size_t)(bn * D_MODELC + c0 + c)) * HWI + yx];
      til[c][yx_l] = v;
    }
  }
  __syncthreads();
  {
    int yx_l = t >> 2, cc = (t & 3) * 8;
    int yx = yx0 + yx_l;
    if (yx < HWI) {
      union { unsigned short u[8]; s8v v; } pk;
#pragma unroll
      for (int j = 0; j < 8; ++j) pk.u[j] = f2bf(til[cc + j][yx_l]);
      *(s8v*)(out + ((size_t)bn * HWI + yx) * D_MODELC + c0 + cc) = pk.v;
    }
  }
}

// ---------------- vol zero + winner init (once) ----------------
__global__ __launch_bounds__(256) void zero_vol_k(unsigned short* __restrict__ vol,
                                                  int* __restrict__ winner) {
  int idx = blockIdx.x * 256 + threadIdx.x;
  // vol: BB*NVOX*128 ushorts = 4.19M = 524288 x uint4
  const int nv16 = (BB * NVOX * 128) / 8;  // 524288 stores of 16B
  if (idx < nv16) {
    uint4 z = make_uint4(0, 0, 0, 0);
    *(uint4*)(vol + (size_t)idx * 8) = z;
  }
  const int nw4 = (BB * NVOX) / 4;  // 8192 stores of int4
  if (idx < nw4) {
    int4 m = make_int4(-1, -1, -1, -1);
    *(int4*)(winner + (size_t)idx * 4) = m;
  }
}

// ---------------- fused LN + dp/att projections (cross), 16 rows/block ----------------
__global__ __launch_bounds__(256) void ln_proj_cross_k(const float* __restrict__ qb,
                                                       const float* __restrict__ g, const float* __restrict__ bbv,
                                                       const float* __restrict__ dpw, const float* __restrict__ dpb,
                                                       const float* __restrict__ aw, const float* __restrict__ ab,
                                                       float* __restrict__ dp_out, float* __restrict__ att_out,
                                                       int M) {
  __shared__ float wl[24][132];
  __shared__ float pr[16][24];
  int t = threadIdx.x;
  for (int i = t; i < 3072; i += 256) {
    int c = i >> 7, k = i & 127;
    wl[c][k] = (c < 16) ? dpw[k * 16 + c] : aw[k * 8 + (c - 16)];
  }
  __syncthreads();
  int r = t >> 4, cg = t & 15;
  int row = blockIdx.x * 16 + r;
  float rv[8];
  {
    float4 v0 = make_float4(0, 0, 0, 0), v1 = v0;
    if (row < M) {
      const float* p = qb + (size_t)row * 128 + cg * 8;
      v0 = *(const float4*)p; v1 = *(const float4*)(p + 4);
    }
    rv[0] = v0.x; rv[1] = v0.y; rv[2] = v0.z; rv[3] = v0.w;
    rv[4] = v1.x; rv[5] = v1.y; rv[6] = v1.z; rv[7] = v1.w;
  }
  float s1 = 0.f, s2 = 0.f;
#pragma unroll
  for (int i = 0; i < 8; ++i) { s1 += rv[i]; s2 += rv[i] * rv[i]; }
#pragma unroll
  for (int msk = 1; msk < 16; msk <<= 1) { s1 += __shfl_xor(s1, msk); s2 += __shfl_xor(s2, msk); }
  float mean = s1 * (1.f / 128.f);
  float var = s2 * (1.f / 128.f) - mean * mean;
  float inv = rsqrtf(var + 1e-5f);
#pragma unroll
  for (int i = 0; i < 8; ++i) {
    int k = cg * 8 + i;
    rv[i] = (rv[i] - mean) * inv * g[k] + bbv[k];
  }
  float p[24];
#pragma unroll
  for (int c = 0; c < 24; ++c) {
    float acc = 0.f;
#pragma unroll
    for (int i = 0; i < 8; ++i) acc += rv[i] * wl[c][cg * 8 + i];
    p[c] = acc;
  }
#pragma unroll
  for (int msk = 1; msk < 16; msk <<= 1) {
#pragma unroll
    for (int c = 0; c < 24; ++c) p[c] += __shfl_xor(p[c], msk);
  }
  if (cg == 0) {
#pragma unroll
    for (int c = 0; c < 24; ++c) pr[r][c] = p[c];
  }
  __syncthreads();
  if (row < M) {
    if (cg < 16) dp_out[row * 16 + cg] = pr[r][cg] + dpb[cg];
    float av = pr[r][16 + (cg & 7)] + ab[cg & 7];
    float mx = av;
#pragma unroll
    for (int msk = 1; msk < 8; msk <<= 1) mx = fmaxf(mx, __shfl_xor(mx, msk));
    float e = expf(av - mx);
    float sm = e;
#pragma unroll
    for (int msk = 1; msk < 8; msk <<= 1) sm += __shfl_xor(sm, msk);
    if (cg < 8) att_out[row * 8 + cg] = e / sm;
  }
}

// ---------------- fused LN + dp/att projections (self), 16 rows/block ----------------
__global__ __launch_bounds__(256) void ln_proj_self_k(const float* __restrict__ qb,
                                                      const float* __restrict__ ref3d,
                                                      const float* __restrict__ g, const float* __restrict__ bbv,
                                                      const float* __restrict__ dpw, const float* __restrict__ dpb,
                                                      const float* __restrict__ aw, const float* __restrict__ ab,
                                                      float* __restrict__ g_out, float* __restrict__ att_out,
                                                      int M) {
  __shared__ float wl[32][132];
  __shared__ float pr[16][32];
  int t = threadIdx.x;
  for (int i = t; i < 4096; i += 256) {
    int c = i >> 7, k = i & 127;
    wl[c][k] = (c < 24) ? dpw[k * 24 + c] : aw[k * 8 + (c - 24)];
  }
  __syncthreads();
  int r = t >> 4, cg = t & 15;
  int row = blockIdx.x * 16 + r;
  float rv[8];
  {
    float4 v0 = make_float4(0, 0, 0, 0), v1 = v0;
    if (row < M) {
      const float* p = qb + (size_t)row * 128 + cg * 8;
      v0 = *(const float4*)p; v1 = *(const float4*)(p + 4);
    }
    rv[0] = v0.x; rv[1] = v0.y; rv[2] = v0.z; rv[3] = v0.w;
    rv[4] = v1.x; rv[5] = v1.y; rv[6] = v1.z; rv[7] = v1.w;
  }
  float s1 = 0.f, s2 = 0.f;
#pragma unroll
  for (int i = 0; i < 8; ++i) { s1 += rv[i]; s2 += rv[i] * rv[i]; }
#pragma unroll
  for (int msk = 1; msk < 16; msk <<= 1) { s1 += __shfl_xor(s1, msk); s2 += __shfl_xor(s2, msk); }
  float mean = s1 * (1.f / 128.f);
  float var = s2 * (1.f / 128.f) - mean * mean;
  float inv = rsqrtf(var + 1e-5f);
#pragma unroll
  for (int i = 0; i < 8; ++i) {
    int k = cg * 8 + i;
    rv[i] = (rv[i] - mean) * inv * g[k] + bbv[k];
  }
  float p[32];
#pragma unroll
  for (int c = 0; c < 32; ++c) {
    float acc = 0.f;
#pragma unroll
    for (int i = 0; i < 8; ++i) acc += rv[i] * wl[c][cg * 8 + i];
    p[c] = acc;
  }
#pragma unroll
  for (int msk = 1; msk < 16; msk <<= 1) {
#pragma unroll
    for (int c = 0; c < 32; ++c) p[c] += __shfl_xor(p[c], msk);
  }
  if (cg == 0) {
#pragma unroll
    for (int c = 0; c < 32; ++c) pr[r][c] = p[c];
  }
  __syncthreads();
  if (row < M) {
    for (int tt = cg; tt < 24; tt += 16) {
      int s = tt / 3, j = tt % 3;
      int pc = (j == 0) ? 1 : ((j == 1) ? 0 : 2);
      g_out[row * 24 + tt] = pr[r][s * 3 + pc] + dpb[s * 3 + pc] + ref3d[row * 3 + pc];
    }
    float av = pr[r][24 + (cg & 7)] + ab[cg & 7];
    float mx = av;
#pragma unroll
    for (int msk = 1; msk < 8; msk <<= 1) mx = fmaxf(mx, __shfl_xor(mx, msk));
    float e = expf(av - mx);
    float sm = e;
#pragma unroll
    for (int msk = 1; msk < 8; msk <<= 1) sm += __shfl_xor(sm, msk);
    if (cg < 8) att_out[row * 8 + cg] = e / sm;
  }
}

// ---------------- cross: gather + MFMA op-GEMM + epilogue -> qb ----------------
__global__ __launch_bounds__(256) void cross_fused_k(const unsigned short* __restrict__ imgT,
                                                     const float* __restrict__ refp,
                                                     const float* __restrict__ dp,
                                                     const float* __restrict__ att,
                                                     const unsigned char* __restrict__ maskp,
                                                     const int* __restrict__ flag,
                                                     const float* __restrict__ invden,
                                                     const float* __restrict__ imc,
                                                     const unsigned short* __restrict__ WcT,
                                                     const float* __restrict__ opb,
                                                     const float* __restrict__ v1,
                                                     const float* __restrict__ v2,
                                                     float* __restrict__ qb, int M) {
  __shared__ __align__(16) int soff[640][4];
  __shared__ __align__(16) float sw[640][4];
  __shared__ __align__(16) unsigned short As[16 * 128];
  __shared__ float awa[16];
  int t = threadIdx.x;
  int m0 = blockIdx.x * 16;
  for (int e = t; e < 640; e += 256) {
    int qi = e / 40, rem = e % 40;
    int n = rem >> 3, s = rem & 7;
    int row = m0 + qi;
    if (row >= M) {
#pragma unroll
      for (int c = 0; c < 4; ++c) { soff[e][c] = 0; sw[e][c] = 0.f; }
      continue;
    }
    int b = row / QQ, q = row - b * QQ;
    int mi = (b * NCAM + n) * QQ + q;
    bool mk = mask_at(maskp, flag, mi);
    float a = mk ? att[row * 8 + s] : 0.f;
    float rx = refp[(size_t)mi * 2 + 0];
    float ry = refp[(size_t)mi * 2 + 1];
    float fx = (rx + dp[row * 16 + s * 2 + 0]) * (float)(WFI - 1);
    float fy = (ry + dp[row * 16 + s * 2 + 1]) * (float)(HFI - 1);
    float x0f = floorf(fx), y0f = floorf(fy);
    int x0 = (int)x0f, y0 = (int)y0f;
    float xd = fx - x0f, yd = fy - y0f;
    int base = (b * NCAM + n) * HWI;
#pragma unroll
    for (int cy = 0; cy < 2; ++cy)
#pragma unroll
      for (int cx = 0; cx < 2; ++cx) {
        int xi = x0 + cx, yi = y0 + cy;
        bool ok = (xi >= 0) & (xi < WFI) & (yi >= 0) & (yi < HFI);
        int xc = min(max(xi, 0), WFI - 1), yc = min(max(yi, 0), HFI - 1);
        soff[e][cy * 2 + cx] = (base + yc * WFI + xc) * 128;
        sw[e][cy * 2 + cx] = ok ? a * (cx ? xd : 1.f - xd) * (cy ? yd : 1.f - yd) : 0.f;
      }
  }
  __syncthreads();
  int qi = t >> 4, ln = t & 15;
  float acc[8] = {};
  float wa = 0.f;
  for (int e = 0; e < 40; ++e) {
    int eb = qi * 40 + e;
    float4 wv = *(const float4*)&sw[eb][0];
    float wsum = wv.x + wv.y + wv.z + wv.w;
    if (wsum != 0.f) {
      int4 ov = *(const int4*)&soff[eb][0];
      s8v p0 = *(const s8v*)(imgT + (size_t)ov.x + ln * 8);
      s8v p1 = *(const s8v*)(imgT + (size_t)ov.y + ln * 8);
      s8v p2 = *(const s8v*)(imgT + (size_t)ov.z + ln * 8);
      s8v p3 = *(const s8v*)(imgT + (size_t)ov.w + ln * 8);
#pragma unroll
      for (int i = 0; i < 8; ++i) {
        acc[i] += wv.x * bf2f((unsigned short)p0[i]) + wv.y * bf2f((unsigned short)p1[i])
                + wv.z * bf2f((unsigned short)p2[i]) + wv.w * bf2f((unsigned short)p3[i]);
      }
      wa += wsum;
    }
  }
  {
    union { unsigned short u[8]; s8v v; } pk;
#pragma unroll
    for (int i = 0; i < 8; ++i) pk.u[i] = f2bf(acc[i]);
    *(s8v*)&As[qi * 128 + ((ln ^ (qi & 7)) << 3)] = pk.v;
    if (ln == 0) awa[qi] = wa;
  }
  __syncthreads();
  int w = t >> 6, l = t & 63;
  int la = l & 15, lb = l >> 4;
  f4 accm[2] = {};
#pragma unroll
  for (int ks = 0; ks < 4; ++ks) {
    s8v af = *(const s8v*)&As[la * 128 + (((ks * 4 + lb) ^ (la & 7)) << 3)];
#pragma unroll
    for (int nt = 0; nt < 2; ++nt) {
      int col = w * 32 + nt * 16 + la;
      s8v bf = *(const s8v*)(WcT + (size_t)col * 128 + ks * 32 + lb * 8);
      accm[nt] = __builtin_amdgcn_mfma_f32_16x16x32_bf16(af, bf, accm[nt], 0, 0, 0);
    }
  }
#pragma unroll
  for (int j = 0; j < 4; ++j) {
    int m = m0 + lb * 4 + j;
    if (m >= M) continue;
    float s0m = invden[m];
    float e1m = s0m * awa[lb * 4 + j];
    float e2m = imc[m];
#pragma unroll
    for (int nt = 0; nt < 2; ++nt) {
      int col = w * 32 + nt * 16 + la;
      float val = accm[nt][j] * s0m + e1m * v1[col] + e2m * v2[col] + opb[col];
      size_t oi = (size_t)m * 128 + col;
      qb[oi] += val;
    }
  }
}

// ---------------- voxel scatter ----------------
__global__ void scatter_winner_k(const int* __restrict__ xi, const int* __restrict__ yi,
                                 const int* __restrict__ zi, int* __restrict__ winner) {
  int i = blockIdx.x * blockDim.x + threadIdx.x;
  if (i >= BQ) return;
  int b = i / QQ;
  int vox = yi[i] * (VXC * VZC) + xi[i] * VZC + zi[i];
  atomicMax(&winner[b * NVOX + vox], i % QQ);
}

__global__ void scatter_write_k(const int* __restrict__ xi, const int* __restrict__ yi,
                                const int* __restrict__ zi, const int* __restrict__ winner,
                                const float* __restrict__ qb, unsigned short* __restrict__ vol) {
  int idx = blockIdx.x * blockDim.x + threadIdx.x;
  if (idx >= BQ * 16) return;
  int g = idx & 15, row = idx >> 4;
  int b = row / QQ, q = row % QQ;
  int vox = yi[row] * (VXC * VZC) + xi[row] * VZC + zi[row];
  if (winner[b * NVOX + vox] != q) return;
  const float* src = qb + (size_t)row * 128 + g * 8;
  float4 a = *(const float4*)src;
  float4 c = *(const float4*)(src + 4);
  union { unsigned short u[8]; s8v v; } pk;
  pk.u[0] = f2bf(a.x); pk.u[1] = f2bf(a.y); pk.u[2] = f2bf(a.z); pk.u[3] = f2bf(a.w);
  pk.u[4] = f2bf(c.x); pk.u[5] = f2bf(c.y); pk.u[6] = f2bf(c.z); pk.u[7] = f2bf(c.w);
  *(s8v*)(vol + ((size_t)b * NVOX + vox) * 128 + g * 8) = pk.v;
}

// ---------------- self: 3d gather + MFMA op-GEMM + epilogue -> qb ----------------
__global__ __launch_bounds__(256) void self_fused_k(const unsigned short* __restrict__ vol,
                                                    const float* __restrict__ gc,
                                                    const float* __restrict__ att,
                                                    const float* __restrict__ many,
                                                    const unsigned short* __restrict__ WcT,
                                                    const float* __restrict__ opb,
                                                    const float* __restrict__ csb,
                                                    float* __restrict__ qb, int M) {
  __shared__ __align__(16) int soff[128][8];
  __shared__ __align__(16) float sw[128][8];
  __shared__ __align__(16) unsigned short As[16 * 128];
  int t = threadIdx.x;
  int m0 = blockIdx.x * 16;
  if (t < 128) {
    int qi = t >> 3, s = t & 7;
    int row = m0 + qi;
    if (row >= M) {
#pragma unroll
      for (int c = 0; c < 8; ++c) { soff[t][c] = 0; sw[t][c] = 0.f; }
    } else {
      int b = row / QQ;
      float a = att[row * 8 + s];
      float fx = (gc[row * 24 + s * 3 + 0] + 1.f) * 0.5f * (float)(VZC - 1);
      float fy = (gc[row * 24 + s * 3 + 1] + 1.f) * 0.5f * (float)(VXC - 1);
      float fz = (gc[row * 24 + s * 3 + 2] + 1.f) * 0.5f * (float)(VYC - 1);
      float x0f = floorf(fx), y0f = floorf(fy), z0f = floorf(fz);
      int x0 = (int)x0f, y0 = (int)y0f, z0 = (int)z0f;
      float xd = fx - x0f, yd = fy - y0f, zd = fz - z0f;
      int base = b * NVOX;
#pragma unroll
      for (int cz = 0; cz < 2; ++cz)
#pragma unroll
        for (int cy = 0; cy < 2; ++cy)
#pragma unroll
          for (int cx = 0; cx < 2; ++cx) {
            int xi = x0 + cx, yi = y0 + cy, zi = z0 + cz;
            bool ok = (xi >= 0) & (xi < VZC) & (yi >= 0) & (yi < VXC) & (zi >= 0) & (zi < VYC);
            int xc = min(max(xi, 0), VZC - 1);
            int yc = min(max(yi, 0), VXC - 1);
            int zc = min(max(zi, 0), VYC - 1);
            int ci = cz * 4 + cy * 2 + cx;
            soff[t][ci] = (base + (zc * VXC + yc) * VZC + xc) * 128;
            sw[t][ci] = ok ? a * (cx ? xd : 1.f - xd) * (cy ? yd : 1.f - yd) * (cz ? zd : 1.f - zd) : 0.f;
          }
    }
  }
  __syncthreads();
  int qi = t >> 4, ln = t & 15;
  float acc[8] = {};
  for (int s = 0; s < 8; ++s) {
    int eb = qi * 8 + s;
#pragma unroll
    for (int c = 0; c < 8; ++c) {
      float w = sw[eb][c];
      if (w != 0.f) {
        s8v p = *(const s8v*)(vol + (size_t)soff[eb][c] + ln * 8);
#pragma unroll
        for (int i = 0; i < 8; ++i) acc[i] += w * bf2f((unsigned short)p[i]);
      }
    }
  }
  {
    union { unsigned short u[8]; s8v v; } pk;
#pragma unroll
    for (int i = 0; i < 8; ++i) pk.u[i] = f2bf(acc[i]);
    *(s8v*)&As[qi * 128 + ((ln ^ (qi & 7)) << 3)] = pk.v;
  }
  __syncthreads();
  int w = t >> 6, l = t & 63;
  int la = l & 15, lb = l >> 4;
  f4 accm[2] = {};
#pragma unroll
  for (int ks = 0; ks < 4; ++ks) {
    s8v af = *(const s8v*)&As[la * 128 + (((ks * 4 + lb) ^ (la & 7)) << 3)];
#pragma unroll
    for (int nt = 0; nt < 2; ++nt) {
      int col = w * 32 + nt * 16 + la;
      s8v bf = *(const s8v*)(WcT + (size_t)col * 128 + ks * 32 + lb * 8);
      accm[nt] = __builtin_amdgcn_mfma_f32_16x16x32_bf16(af, bf, accm[nt], 0, 0, 0);
    }
  }
#pragma unroll
  for (int j = 0; j < 4; ++j) {
    int m = m0 + lb * 4 + j;
    if (m >= M) continue;
    float s0m = many[m];
#pragma unroll
    for (int nt = 0; nt < 2; ++nt) {
      int col = w * 32 + nt * 16 + la;
      float val = accm[nt][j] * s0m + s0m * csb[col] + opb[col];
      size_t oi = (size_t)m * 128 + col;
      qb[oi] += val;
    }
  }
}

// ---------------- fused FFN: LN + ff1 + GELU + ff2 + residual ----------------
__global__ __launch_bounds__(512) void ffn_k(float* __restrict__ qb,
                                             const float* __restrict__ lng, const float* __restrict__ lnb,
                                             const unsigned short* __restrict__ W1T, const float* __restrict__ b1,
                                             const unsigned short* __restrict__ W2T, const float* __restrict__ b2,
                                             int M) {
  __shared__ __align__(16) unsigned short As[16 * 128];
  __shared__ __align__(16) unsigned short Hs[16 * 512];
  int t = threadIdx.x;
  int m0 = blockIdx.x * 16;
  {
    int r = t >> 5, cg = t & 31;
    int gm = m0 + r;
    float4 v = make_float4(0, 0, 0, 0);
    if (gm < M) v = *(const float4*)(qb + (size_t)gm * 128 + cg * 4);
    float s1 = v.x + v.y + v.z + v.w;
    float s2 = v.x * v.x + v.y * v.y + v.z * v.z + v.w * v.w;
#pragma unroll
    for (int msk = 1; msk < 32; msk <<= 1) { s1 += __shfl_xor(s1, msk); s2 += __shfl_xor(s2, msk); }
    float mean = s1 * (1.f / 128.f);
    float var = s2 * (1.f / 128.f) - mean * mean;
    float inv = rsqrtf(var + 1e-5f);
    float lv[4] = {v.x, v.y, v.z, v.w};
    union { unsigned short u[4]; ushort4 v4; } pk;
#pragma unroll
    for (int i = 0; i < 4; ++i) {
      int k = cg * 4 + i;
      pk.u[i] = f2bf((lv[i] - mean) * inv * lng[k] + lnb[k]);
    }
    int c8 = cg >> 1, half = cg & 1;
    *(ushort4*)&As[r * 128 + ((c8 ^ (r & 7)) << 3) + half * 4] = pk.v4;
  }
  __syncthreads();
  int w = t >> 6, l = t & 63;
  int la = l & 15, lb = l >> 4;
  {
    f4 acc1[4] = {};
#pragma unroll
    for (int ti = 0; ti < 4; ++ti) {
      int col = (w * 4 + ti) * 16 + la;
#pragma unroll
      for (int ks = 0; ks < 4; ++ks) {
        s8v af = *(const s8v*)&As[la * 128 + (((ks * 4 + lb) ^ (la & 7)) << 3)];
        s8v bf = *(const s8v*)(W1T + (size_t)col * 128 + ks * 32 + lb * 8);
        acc1[ti] = __builtin_amdgcn_mfma_f32_16x16x32_bf16(af, bf, acc1[ti], 0, 0, 0);
      }
    }
#pragma unroll
    for (int ti = 0; ti < 4; ++ti) {
      int col = (w * 4 + ti) * 16 + la;
      int chunk = col >> 3, idx = col & 7;
#pragma unroll
      for (int j = 0; j < 4; ++j) {
        int m = lb * 4 + j;
        float val = acc1[ti][j] + b1[col];
        val = 0.5f * val * (1.f + erff(val * 0.70710678118654752f));
        Hs[m * 512 + ((chunk ^ (m & 7)) << 3) + idx] = f2bf(val);
      }
    }
  }
  __syncthreads();
  {
    f4 acc2 = {};
    int col = w * 16 + la;
#pragma unroll
    for (int ks = 0; ks < 16; ++ks) {
      s8v af = *(const s8v*)&Hs[la * 512 + (((ks * 4 + lb) ^ (la & 7)) << 3)];
      s8v bf = *(const s8v*)(W2T + (size_t)col * 512 + ks * 32 + lb * 8);
      acc2 = __builtin_amdgcn_mfma_f32_16x16x32_bf16(af, bf, acc2, 0, 0, 0);
    }
#pragma unroll
    for (int j = 0; j < 4; ++j) {
      int m = m0 + lb * 4 + j;
      if (m >= M) continue;
      size_t oi = (size_t)m * 128 + col;
      qb[oi] += acc2[j] + b2[col];
    }
  }
}

// ---------------- small f32 128x128x128 batched GEMM (weight precompute) ----------------
struct P5 { const float* a[5]; const float* b[5]; float* c[5]; };

__global__ __launch_bounds__(256) void small_mm_k(P5 ps) {
  const float* A = ps.a[blockIdx.z];
  const float* Bm = ps.b[blockIdx.z];
  float* C = ps.c[blockIdx.z];
  __shared__ float As_[32][64];
  __shared__ float Ws_[32][64];
  int m0 = blockIdx.x * 64, n0 = blockIdx.y * 64, tid = threadIdx.x;
  float acc[4][4] = {};
  int mr = (tid >> 4) * 4, nc = (tid & 15) * 4;
  for (int k0 = 0; k0 < 128; k0 += 32) {
    {
      int r = tid >> 2, kq = (tid & 3) * 8;
      const float* ap = A + (size_t)(m0 + r) * 128 + k0 + kq;
      float4 v0 = *(const float4*)ap, v1 = *(const float4*)(ap + 4);
      As_[kq + 0][r] = v0.x; As_[kq + 1][r] = v0.y; As_[kq + 2][r] = v0.z; As_[kq + 3][r] = v0.w;
      As_[kq + 4][r] = v1.x; As_[kq + 5][r] = v1.y; As_[kq + 6][r] = v1.z; As_[kq + 7][r] = v1.w;
    }
    {
      int kr = tid >> 3, nq = (tid & 7) * 8;
      const float* wp = Bm + (size_t)(k0 + kr) * 128 + n0 + nq;
      *(float4*)&Ws_[kr][nq] = *(const float4*)wp;
      *(float4*)&Ws_[kr][nq + 4] = *(const float4*)(wp + 4);
    }
    __syncthreads();
#pragma unroll
    for (int kk = 0; kk < 32; ++kk) {
      float4 av = *(const float4*)&As_[kk][mr];
      float4 bv = *(const float4*)&Ws_[kk][nc];
      float a_[4] = {av.x, av.y, av.z, av.w};
      float b_[4] = {bv.x, bv.y, bv.z, bv.w};
#pragma unroll
      for (int i = 0; i < 4; ++i)
#pragma unroll
        for (int j = 0; j < 4; ++j) acc[i][j] += a_[i] * b_[j];
    }
    __syncthreads();
  }
#pragma unroll
  for (int i = 0; i < 4; ++i) {
    float4 r;
    r.x = acc[i][0]; r.y = acc[i][1]; r.z = acc[i][2]; r.w = acc[i][3];
    *(float4*)(C + (size_t)(m0 + mr + i) * 128 + n0 + nc) = r;
  }
}

// ---------------- per-layer constant vectors ----------------
__global__ void pre_vec_k(const float* __restrict__ c_vp_b, const float* __restrict__ c_w_b,
                          const float* __restrict__ s_vp_b, const float* __restrict__ s_w_b,
                          const float* __restrict__ c_op_w, const float* __restrict__ s_op_w,
                          const float* __restrict__ Qbuf,
                          float* __restrict__ v1buf, float* __restrict__ v2buf,
                          float* __restrict__ csbuf) {
  int L = blockIdx.x, n = threadIdx.x;
  const float* vpb = L < 3 ? c_vp_b + L * 128 : s_vp_b + (L - 3) * 128;
  const float* wb = L < 3 ? c_w_b + L * 128 : s_w_b + (L - 3) * 128;
  const float* op = L < 3 ? c_op_w + (size_t)L * 16384 : s_op_w + (size_t)(L - 3) * 16384;
  const float* Q = Qbuf + (size_t)L * 16384;
  float a = 0.f, c = 0.f;
  for (int k = 0; k < 128; ++k) {
    a += vpb[k] * Q[k * 128 + n];
    c += wb[k] * op[k * 128 + n];
  }
  if (L < 3) { v1buf[L * 128 + n] = a; v2buf[L * 128 + n] = c; }
  else csbuf[(L - 3) * 128 + n] = a + c;
}

// ---------------- weight convert+transpose to bf16 [N][K] ----------------
__global__ void wconv_k(const float* __restrict__ Wcbuf,
                        const float* __restrict__ cf1, const float* __restrict__ sf1,
                        const float* __restrict__ cf2, const float* __restrict__ sf2,
                        unsigned short* __restrict__ WcT, unsigned short* __restrict__ f1T,
                        unsigned short* __restrict__ f2T) {
  int widx = blockIdx.y;
  const float* src; unsigned short* dst; int K, N, elems;
  if (widx < 5) { src = Wcbuf + (size_t)widx * 16384; dst = WcT + (size_t)widx * 16384; K = 128; N = 128; elems = 16384; }
  else if (widx < 10) {
    int L = widx - 5;
    src = (L < 3) ? cf1 + (size_t)L * 65536 : sf1 + (size_t)(L - 3) * 65536;
    dst = f1T + (size_t)L * 65536; K = 128; N = 512; elems = 65536;
  } else {
    int L = widx - 10;
    src = (L < 3) ? cf2 + (size_t)L * 65536 : sf2 + (size_t)(L - 3) * 65536;
    dst = f2T + (size_t)L * 65536; K = 512; N = 128; elems = 65536;
  }
  int e = (blockIdx.x * 256 + threadIdx.x) * 4;
  if (e >= elems) return;
  int k = e % K, n = e / K;
  ushort4 o;
  o.x = f2bf(src[(size_t)(k + 0) * N + n]);
  o.y = f2bf(src[(size_t)(k + 1) * N + n]);
  o.z = f2bf(src[(size_t)(k + 2) * N + n]);
  o.w = f2bf(src[(size_t)(k + 3) * N + n]);
  *(ushort4*)(dst + e) = o;
}

// ---------------- classifier ----------------
__global__ void classifier_k(const float* __restrict__ qb, const float* __restrict__ cw,
                             const float* __restrict__ cb, float* __restrict__ out) {
  __shared__ float red[2][4];
  int row = blockIdx.x, t = threadIdx.x;
  float v = qb[row * 128 + t];
  float p0 = v * cw[t * 4 + 0];
  float p1 = v * cw[t * 4 + 1];
  float p2 = v * cw[t * 4 + 2];
  float p3 = v * cw[t * 4 + 3];
#pragma unroll
  for (int off = 32; off > 0; off >>= 1) {
    p0 += __shfl_down(p0, off);
    p1 += __shfl_down(p1, off);
    p2 += __shfl_down(p2, off);
    p3 += __shfl_down(p3, off);
  }
  int lane = t & 63, w = t >> 6;
  if (lane == 0) { red[w][0] = p0; red[w][1] = p1; red[w][2] = p2; red[w][3] = p3; }
  __syncthreads();
  if (t < 4) out[row * 4 + t] = red[0][t] + red[1][t] + cb[t];
}

extern "C" void kernel_launch(void* const* d_in, const int* in_sizes, int n_in,
                              void* d_out, int out_size, void* d_ws, size_t ws_size,
                              hipStream_t stream) {
  (void)in_sizes; (void)n_in; (void)out_size; (void)ws_size;
  const float* query = (const float*)d_in[0];
  const float* ref_points = (const float*)d_in[1];
  const float* ref3d = (const float*)d_in[2];
  const float* imgf = (const float*)d_in[3];
  const unsigned char* maskp = (const unsigned char*)d_in[4];
  const int* x_idx = (const int*)d_in[5];
  const int* y_idx = (const int*)d_in[6];
  const int* z_idx = (const int*)d_in[7];
  const float* c_ln1_g = (const float*)d_in[8];
  const float* c_ln1_b = (const float*)d_in[9];
  const float* c_dp_w = (const float*)d_in[10];
  const float* c_dp_b = (const float*)d_in[11];
  const float* c_a_w = (const float*)d_in[12];
  const float* c_a_b = (const float*)d_in[13];
  const float* c_w_w = (const float*)d_in[14];
  const float* c_w_b = (const float*)d_in[15];
  const float* c_vp_w = (const float*)d_in[16];
  const float* c_vp_b = (const float*)d_in[17];
  const float* c_op_w = (const float*)d_in[18];
  const float* c_op_b = (const float*)d_in[19];
  const float* c_ln2_g = (const float*)d_in[20];
  const float* c_ln2_b = (const float*)d_in[21];
  const float* c_ff1_w = (const float*)d_in[22];
  const float* c_ff1_b = (const float*)d_in[23];
  const float* c_ff2_w = (const float*)d_in[24];
  const float* c_ff2_b = (const float*)d_in[25];
  const float* s_ln1_g = (const float*)d_in[26];
  const float* s_ln1_b = (const float*)d_in[27];
  const float* s_dp_w = (const float*)d_in[28];
  const float* s_dp_b = (const float*)d_in[29];
  const float* s_a_w = (const float*)d_in[30];
  const float* s_a_b = (const float*)d_in[31];
  const float* s_w_w = (const float*)d_in[32];
  const float* s_w_b = (const float*)d_in[33];
  const float* s_vp_w = (const float*)d_in[34];
  const float* s_vp_b = (const float*)d_in[35];
  const float* s_op_w = (const float*)d_in[36];
  const float* s_op_b = (const float*)d_in[37];
  const float* s_ln2_g = (const float*)d_in[38];
  const float* s_ln2_b = (const float*)d_in[39];
  const float* s_ff1_w = (const float*)d_in[40];
  const float* s_ff1_b = (const float*)d_in[41];
  const float* s_ff2_w = (const float*)d_in[42];
  const float* s_ff2_b = (const float*)d_in[43];
  const float* cls_w = (const float*)d_in[44];
  const float* cls_b = (const float*)d_in[45];
  float* out = (float*)d_out;

  char* ws = (char*)d_ws;
  size_t off = 0;
  auto carve = [&](size_t bytes) -> char* {
    char* p = ws + off;
    off += (bytes + 255) & ~(size_t)255;
    return p;
  };
  int* flag = (int*)carve(256);
  float* invden = (float*)carve(BQ * 4);
  float* imc = (float*)carve(BQ * 4);
  float* many = (float*)carve(BQ * 4);
  float* dpg = (float*)carve((size_t)BQ * 24 * 4);
  float* attb = (float*)carve((size_t)BQ * 8 * 4);
  float* qb = (float*)carve((size_t)BQ * 128 * 4);
  int* winner = (int*)carve((size_t)BB * NVOX * 4);
  float* Qbuf = (float*)carve((size_t)5 * 16384 * 4);
  float* Wcbuf = (float*)carve((size_t)5 * 16384 * 4);
  unsigned short* WcT = (unsigned short*)carve((size_t)5 * 16384 * 2);
  unsigned short* f1T = (unsigned short*)carve((size_t)5 * 65536 * 2);
  unsigned short* f2T = (unsigned short*)carve((size_t)5 * 65536 * 2);
  float* v1buf = (float*)carve(3 * 128 * 4);
  float* v2buf = (float*)carve(3 * 128 * 4);
  float* csbuf = (float*)carve(2 * 128 * 4);
  unsigned short* imgT = (unsigned short*)carve((size_t)BB * NCAM * HWI * 128 * 2);
  unsigned short* vol = (unsigned short*)carve((size_t)BB * NVOX * 128 * 2);

  const int M = BQ;
  const int GB16 = (M + 15) / 16;  // 313

  // ---- setup ----
  detect_mask_k<<<1, 256, 0, stream>>>(maskp, flag);
  precompute_k<<<(BQ + 255) / 256, 256, 0, stream>>>(maskp, flag, invden, imc, many);
  transpose_img_k<<<dim3((HWI + 63) / 64, 4, BB * NCAM), 256, 0, stream>>>(imgf, imgT);
  {
    P5 pq, pw;
    for (int L = 0; L < 5; ++L) {
      pq.a[L] = (L < 3) ? c_w_w + (size_t)L * 16384 : s_w_w + (size_t)(L - 3) * 16384;
      pq.b[L] = (L < 3) ? c_op_w + (size_t)L * 16384 : s_op_w + (size_t)(L - 3) * 16384;
      pq.c[L] = Qbuf + (size_t)L * 16384;
      pw.a[L] = (L < 3) ? c_vp_w + (size_t)L * 16384 : s_vp_w + (size_t)(L - 3) * 16384;
      pw.b[L] = Qbuf + (size_t)L * 16384;
      pw.c[L] = Wcbuf + (size_t)L * 16384;
    }
    small_mm_k<<<dim3(2, 2, 5), 256, 0, stream>>>(pq);
    small_mm_k<<<dim3(2, 2, 5), 256, 0, stream>>>(pw);
  }
  pre_vec_k<<<5, 128, 0, stream>>>(c_vp_b, c_w_b, s_vp_b, s_w_b, c_op_w, s_op_w, Qbuf,
                                   v1buf, v2buf, csbuf);
  wconv_k<<<dim3(64, 15), 256, 0, stream>>>(Wcbuf, c_ff1_w, s_ff1_w, c_ff2_w, s_ff2_w,
                                            WcT, f1T, f2T);
  zero_vol_k<<<(BB * NVOX * 128 / 8 + 255) / 256, 256, 0, stream>>>(vol, winner);
  scatter_winner_k<<<(BQ + 255) / 256, 256, 0, stream>>>(x_idx, y_idx, z_idx, winner);
  hipMemcpyAsync(qb, query, (size_t)BQ * 128 * 4, hipMemcpyDeviceToDevice, stream);

  // ---- cross attention stack ----
  for (int i = 0; i < NCROSS; ++i) {
    ln_proj_cross_k<<<GB16, 256, 0, stream>>>(qb, c_ln1_g + i * 128, c_ln1_b + i * 128,
                                              c_dp_w + (size_t)i * 128 * 16, c_dp_b + i * 16,
                                              c_a_w + (size_t)i * 128 * 8, c_a_b + i * 8,
                                              dpg, attb, M);
    cross_fused_k<<<GB16, 256, 0, stream>>>(imgT, ref_points, dpg, attb, maskp, flag,
                                            invden, imc, WcT + (size_t)i * 16384,
                                            c_op_b + i * 128, v1buf + i * 128, v2buf + i * 128,
                                            qb, M);
    ffn_k<<<GB16, 512, 0, stream>>>(qb, c_ln2_g + i * 128, c_ln2_b + i * 128,
                                    f1T + (size_t)i * 65536, c_ff1_b + i * 512,
                                    f2T + (size_t)i * 65536, c_ff2_b + i * 128, M);
  }

  // ---- self attention stack ----
  for (int i = 0; i < NSELF; ++i) {
    scatter_write_k<<<(BQ * 16 + 255) / 256, 256, 0, stream>>>(x_idx, y_idx, z_idx, winner, qb, vol);
    ln_proj_self_k<<<GB16, 256, 0, stream>>>(qb, ref3d, s_ln1_g + i * 128, s_ln1_b + i * 128,
                                             s_dp_w + (size_t)i * 128 * 24, s_dp_b + i * 24,
                                             s_a_w + (size_t)i * 128 * 8, s_a_b + i * 8,
                                             dpg, attb, M);
    self_fused_k<<<GB16, 256, 0, stream>>>(vol, dpg, attb, many,
                                           WcT + (size_t)(3 + i) * 16384, s_op_b + i * 128,
                                           csbuf + i * 128, qb, M);
    ffn_k<<<GB16, 512, 0, stream>>>(qb, s_ln2_g + i * 128, s_ln2_b + i * 128,
                                    f1T + (size_t)(3 + i) * 65536, s_ff1_b + i * 512,
                                    f2T + (size_t)(3 + i) * 65536, s_ff2_b + i * 128, M);
  }

  classifier_k<<<BQ, 128, 0, stream>>>(qb, cls_w, cls_b, out);
}

// Round 5
// 471.534 us; speedup vs baseline: 1.8497x; 1.1360x over previous
//
#include <hip/hip_runtime.h>
#include <math.h>

#define D_MODELC 128
#define NSAMP 8
#define DFF 512
#define NCROSS 3
#define NSELF 2
#define BB 2
#define NCAM 5
#define QQ 2500
#define HFI 24
#define WFI 77
#define VXC 32
#define VYC 16
#define VZC 32
#define BQ (BB*QQ)
#define HWI (HFI*WFI)
#define NVOX (VYC*VXC*VZC)

typedef float f4 __attribute__((ext_vector_type(4)));
typedef short s8v __attribute__((ext_vector_type(8)));

__device__ __forceinline__ unsigned short f2bf(float f) {
  union { float f; unsigned u; } v; v.f = f;
  unsigned r = v.u + 0x7FFFu + ((v.u >> 16) & 1u);
  return (unsigned short)(r >> 16);
}
__device__ __forceinline__ float bf2f(unsigned short u) {
  union { unsigned u; float f; } v; v.u = ((unsigned)u) << 16; return v.f;
}

__device__ __forceinline__ bool mask_at(const unsigned char* m, int fl, int idx) {
  if (fl) return m[idx] != 0;
  return ((const int*)m)[idx] != 0;
}

// ---------------- mask detect + per-(b,q) stats (one block) ----------------
__global__ __launch_bounds__(1024) void mask_k(const unsigned char* __restrict__ m,
                                               int* __restrict__ flag,
                                               float* __restrict__ invden, float* __restrict__ imc,
                                               float* __restrict__ many) {
  __shared__ int f;
  if (threadIdx.x == 0) f = 0;
  __syncthreads();
  const int total = BB * NCAM * QQ;
  int loc = 0;
  for (int i = threadIdx.x; i < total; i += 1024)
    if ((i & 3) && m[i]) loc = 1;
  if (loc) atomicOr(&f, 1);
  __syncthreads();
  int fl = f;
  if (threadIdx.x == 0) *flag = fl;
  for (int i = threadIdx.x; i < BQ; i += 1024) {
    int b = i / QQ, q = i % QQ;
    float cnt = 0.f;
    for (int n = 0; n < NCAM; ++n)
      cnt += mask_at(m, fl, (b * NCAM + n) * QQ + q) ? 1.f : 0.f;
    float inv = 1.f / (cnt + 1e-6f);
    invden[i] = inv;
    imc[i] = cnt * inv;
    many[i] = cnt > 0.f ? 1.f : 0.f;
  }
}

// ---------------- image transpose [BN,C,H,W] f32 -> [BN,H,W,C] bf16 ----------------
__global__ __launch_bounds__(256) void transpose_img_k(const float* __restrict__ in,
                                                       unsigned short* __restrict__ out) {
  __shared__ float til[32][65];
  int bn = blockIdx.z;
  int c0 = blockIdx.y * 32;
  int yx0 = blockIdx.x * 64;
  int t = threadIdx.x;
  {
    int yx_l = t & 63, c_l = t >> 6;
    int yx = yx0 + yx_l;
#pragma unroll
    for (int i = 0; i < 8; ++i) {
      int c = c_l + 4 * i;
      float v = 0.f;
      if (yx < HWI) v = in[((size_t)(bn * D_MODELC + c0 + c)) * HWI + yx];
      til[c][yx_l] = v;
    }
  }
  __syncthreads();
  {
    int yx_l = t >> 2, cc = (t & 3) * 8;
    int yx = yx0 + yx_l;
    if (yx < HWI) {
      union { unsigned short u[8]; s8v v; } pk;
#pragma unroll
      for (int j = 0; j < 8; ++j) pk.u[j] = f2bf(til[cc + j][yx_l]);
      *(s8v*)(out + ((size_t)bn * HWI + yx) * D_MODELC + c0 + cc) = pk.v;
    }
  }
}

// ---------------- vol zero + winner init ----------------
__global__ __launch_bounds__(256) void zero_vol_k(unsigned short* __restrict__ vol,
                                                  int* __restrict__ winner) {
  int idx = blockIdx.x * 256 + threadIdx.x;
  const int nv16 = (BB * NVOX * 128) / 8;
  if (idx < nv16) {
    uint4 z = make_uint4(0, 0, 0, 0);
    *(uint4*)(vol + (size_t)idx * 8) = z;
  }
  const int nw4 = (BB * NVOX) / 4;
  if (idx < nw4) {
    int4 m = make_int4(-1, -1, -1, -1);
    *(int4*)(winner + (size_t)idx * 4) = m;
  }
}

__global__ void scatter_winner_k(const int* __restrict__ xi, const int* __restrict__ yi,
                                 const int* __restrict__ zi, int* __restrict__ winner) {
  int i = blockIdx.x * blockDim.x + threadIdx.x;
  if (i >= BQ) return;
  int b = i / QQ;
  int vox = yi[i] * (VXC * VZC) + xi[i] * VZC + zi[i];
  atomicMax(&winner[b * NVOX + vox], i % QQ);
}

__global__ void scatter_write_k(const int* __restrict__ xi, const int* __restrict__ yi,
                                const int* __restrict__ zi, const int* __restrict__ winner,
                                const float* __restrict__ qb, unsigned short* __restrict__ vol) {
  int idx = blockIdx.x * blockDim.x + threadIdx.x;
  if (idx >= BQ * 16) return;
  int g = idx & 15, row = idx >> 4;
  int b = row / QQ, q = row % QQ;
  int vox = yi[row] * (VXC * VZC) + xi[row] * VZC + zi[row];
  if (winner[b * NVOX + vox] != q) return;
  const float* src = qb + (size_t)row * 128 + g * 8;
  float4 a = *(const float4*)src;
  float4 c = *(const float4*)(src + 4);
  union { unsigned short u[8]; s8v v; } pk;
  pk.u[0] = f2bf(a.x); pk.u[1] = f2bf(a.y); pk.u[2] = f2bf(a.z); pk.u[3] = f2bf(a.w);
  pk.u[4] = f2bf(c.x); pk.u[5] = f2bf(c.y); pk.u[6] = f2bf(c.z); pk.u[7] = f2bf(c.w);
  *(s8v*)(vol + ((size_t)b * NVOX + vox) * 128 + g * 8) = pk.v;
}

// ---------------- setup: Qbuf = w_w@op_w (z<5) + f1T/f2T bf16 transpose (z>=5) ----------------
__global__ __launch_bounds__(256) void tpre_k(const float* __restrict__ c_w_w, const float* __restrict__ s_w_w,
                                              const float* __restrict__ c_op_w, const float* __restrict__ s_op_w,
                                              const float* __restrict__ cf1, const float* __restrict__ sf1,
                                              const float* __restrict__ cf2, const float* __restrict__ sf2,
                                              float* __restrict__ Qbuf,
                                              unsigned short* __restrict__ f1T, unsigned short* __restrict__ f2T) {
  __shared__ float As_[32][64];
  __shared__ float Ws_[32][64];
  int z = blockIdx.z, tid = threadIdx.x;
  if (z < 5) {
    const float* A = (z < 3) ? c_w_w + (size_t)z * 16384 : s_w_w + (size_t)(z - 3) * 16384;
    const float* Bm = (z < 3) ? c_op_w + (size_t)z * 16384 : s_op_w + (size_t)(z - 3) * 16384;
    float* C = Qbuf + (size_t)z * 16384;
    int m0 = blockIdx.x * 64, n0 = blockIdx.y * 64;
    float acc[4][4] = {};
    int mr = (tid >> 4) * 4, nc = (tid & 15) * 4;
    for (int k0 = 0; k0 < 128; k0 += 32) {
      {
        int r = tid >> 2, kq = (tid & 3) * 8;
        const float* ap = A + (size_t)(m0 + r) * 128 + k0 + kq;
        float4 v0 = *(const float4*)ap, v1 = *(const float4*)(ap + 4);
        As_[kq + 0][r] = v0.x; As_[kq + 1][r] = v0.y; As_[kq + 2][r] = v0.z; As_[kq + 3][r] = v0.w;
        As_[kq + 4][r] = v1.x; As_[kq + 5][r] = v1.y; As_[kq + 6][r] = v1.z; As_[kq + 7][r] = v1.w;
      }
      {
        int kr = tid >> 3, nq = (tid & 7) * 8;
        const float* wp = Bm + (size_t)(k0 + kr) * 128 + n0 + nq;
        *(float4*)&Ws_[kr][nq] = *(const float4*)wp;
        *(float4*)&Ws_[kr][nq + 4] = *(const float4*)(wp + 4);
      }
      __syncthreads();
#pragma unroll
      for (int kk = 0; kk < 32; ++kk) {
        float4 av = *(const float4*)&As_[kk][mr];
        float4 bv = *(const float4*)&Ws_[kk][nc];
        float a_[4] = {av.x, av.y, av.z, av.w};
        float b_[4] = {bv.x, bv.y, bv.z, bv.w};
#pragma unroll
        for (int i = 0; i < 4; ++i)
#pragma unroll
          for (int j = 0; j < 4; ++j) acc[i][j] += a_[i] * b_[j];
      }
      __syncthreads();
    }
#pragma unroll
    for (int i = 0; i < 4; ++i) {
      float4 r;
      r.x = acc[i][0]; r.y = acc[i][1]; r.z = acc[i][2]; r.w = acc[i][3];
      *(float4*)(C + (size_t)(m0 + mr + i) * 128 + n0 + nc) = r;
    }
  } else {
    int bid = (z - 5) * 4 + blockIdx.y * 2 + blockIdx.x;
    int widx = bid >> 6, chunk = bid & 63;
    const float* src; unsigned short* dst; int K, N;
    if (widx < 5) {
      src = (widx < 3) ? cf1 + (size_t)widx * 65536 : sf1 + (size_t)(widx - 3) * 65536;
      dst = f1T + (size_t)widx * 65536; K = 128; N = 512;
    } else {
      int L = widx - 5;
      src = (L < 3) ? cf2 + (size_t)L * 65536 : sf2 + (size_t)(L - 3) * 65536;
      dst = f2T + (size_t)L * 65536; K = 512; N = 128;
    }
    int e = (chunk * 256 + tid) * 4;
    int k = e % K, n = e / K;
    ushort4 o;
    o.x = f2bf(src[(size_t)(k + 0) * N + n]);
    o.y = f2bf(src[(size_t)(k + 1) * N + n]);
    o.z = f2bf(src[(size_t)(k + 2) * N + n]);
    o.w = f2bf(src[(size_t)(k + 3) * N + n]);
    *(ushort4*)(dst + e) = o;
  }
}

// ---------------- setup: Wcbuf = vp_w @ Qbuf ----------------
struct P5 { const float* a[5]; const float* b[5]; float* c[5]; };

__global__ __launch_bounds__(256) void small_mm_k(P5 ps) {
  const float* A = ps.a[blockIdx.z];
  const float* Bm = ps.b[blockIdx.z];
  float* C = ps.c[blockIdx.z];
  __shared__ float As_[32][64];
  __shared__ float Ws_[32][64];
  int m0 = blockIdx.x * 64, n0 = blockIdx.y * 64, tid = threadIdx.x;
  float acc[4][4] = {};
  int mr = (tid >> 4) * 4, nc = (tid & 15) * 4;
  for (int k0 = 0; k0 < 128; k0 += 32) {
    {
      int r = tid >> 2, kq = (tid & 3) * 8;
      const float* ap = A + (size_t)(m0 + r) * 128 + k0 + kq;
      float4 v0 = *(const float4*)ap, v1 = *(const float4*)(ap + 4);
      As_[kq + 0][r] = v0.x; As_[kq + 1][r] = v0.y; As_[kq + 2][r] = v0.z; As_[kq + 3][r] = v0.w;
      As_[kq + 4][r] = v1.x; As_[kq + 5][r] = v1.y; As_[kq + 6][r] = v1.z; As_[kq + 7][r] = v1.w;
    }
    {
      int kr = tid >> 3, nq = (tid & 7) * 8;
      const float* wp = Bm + (size_t)(k0 + kr) * 128 + n0 + nq;
      *(float4*)&Ws_[kr][nq] = *(const float4*)wp;
      *(float4*)&Ws_[kr][nq + 4] = *(const float4*)(wp + 4);
    }
    __syncthreads();
#pragma unroll
    for (int kk = 0; kk < 32; ++kk) {
      float4 av = *(const float4*)&As_[kk][mr];
      float4 bv = *(const float4*)&Ws_[kk][nc];
      float a_[4] = {av.x, av.y, av.z, av.w};
      float b_[4] = {bv.x, bv.y, bv.z, bv.w};
#pragma unroll
      for (int i = 0; i < 4; ++i)
#pragma unroll
        for (int j = 0; j < 4; ++j) acc[i][j] += a_[i] * b_[j];
    }
    __syncthreads();
  }
#pragma unroll
  for (int i = 0; i < 4; ++i) {
    float4 r;
    r.x = acc[i][0]; r.y = acc[i][1]; r.z = acc[i][2]; r.w = acc[i][3];
    *(float4*)(C + (size_t)(m0 + mr + i) * 128 + n0 + nc) = r;
  }
}

// ---------------- setup: WcT conv (y<5) + pre_vec (y==5) ----------------
__global__ __launch_bounds__(256) void wpre_k(const float* __restrict__ Wcbuf,
                                              unsigned short* __restrict__ WcT,
                                              const float* __restrict__ c_vp_b, const float* __restrict__ c_w_b,
                                              const float* __restrict__ s_vp_b, const float* __restrict__ s_w_b,
                                              const float* __restrict__ c_op_w, const float* __restrict__ s_op_w,
                                              const float* __restrict__ Qbuf,
                                              float* __restrict__ v1buf, float* __restrict__ v2buf,
                                              float* __restrict__ csbuf) {
  int t = threadIdx.x;
  if (blockIdx.y < 5) {
    int L = blockIdx.y;
    const float* src = Wcbuf + (size_t)L * 16384;
    unsigned short* dst = WcT + (size_t)L * 16384;
    int e = (blockIdx.x * 256 + t) * 4;
    int k = e & 127, n = e >> 7;
    ushort4 o;
    o.x = f2bf(src[(size_t)(k + 0) * 128 + n]);
    o.y = f2bf(src[(size_t)(k + 1) * 128 + n]);
    o.z = f2bf(src[(size_t)(k + 2) * 128 + n]);
    o.w = f2bf(src[(size_t)(k + 3) * 128 + n]);
    *(ushort4*)(dst + e) = o;
  } else if (blockIdx.x < 5 && t < 128) {
    int L = blockIdx.x, n = t;
    const float* vpb = L < 3 ? c_vp_b + L * 128 : s_vp_b + (L - 3) * 128;
    const float* wb = L < 3 ? c_w_b + L * 128 : s_w_b + (L - 3) * 128;
    const float* op = L < 3 ? c_op_w + (size_t)L * 16384 : s_op_w + (size_t)(L - 3) * 16384;
    const float* Q = Qbuf + (size_t)L * 16384;
    float a = 0.f, c = 0.f;
    for (int k = 0; k < 128; ++k) {
      a += vpb[k] * Q[k * 128 + n];
      c += wb[k] * op[k * 128 + n];
    }
    if (L < 3) { v1buf[L * 128 + n] = a; v2buf[L * 128 + n] = c; }
    else csbuf[(L - 3) * 128 + n] = a + c;
  }
}

// ================= CROSS MEGA: 3 layers fully fused, 16 rows/block, 512 thr =================
__global__ __launch_bounds__(512) void cross_mega_k(
    const float* __restrict__ query, const float* __restrict__ refp,
    const unsigned char* __restrict__ maskp, const int* __restrict__ flagp,
    const float* __restrict__ invden, const float* __restrict__ imc,
    const unsigned short* __restrict__ imgT,
    const float* __restrict__ ln1g, const float* __restrict__ ln1b,
    const float* __restrict__ dpw_, const float* __restrict__ dpb_,
    const float* __restrict__ aw_, const float* __restrict__ ab_,
    const unsigned short* __restrict__ WcT, const float* __restrict__ opb_,
    const float* __restrict__ v1_, const float* __restrict__ v2_,
    const float* __restrict__ ln2g, const float* __restrict__ ln2b,
    const unsigned short* __restrict__ f1T, const float* __restrict__ b1_,
    const unsigned short* __restrict__ f2T, const float* __restrict__ b2_,
    float* __restrict__ qb, int M) {
  __shared__ float qtile[16][128];
  __shared__ float pr[16][32];
  __shared__ float attL[16][8];
  __shared__ float awa[16];
  __shared__ __align__(16) unsigned short As[16 * 128];
  __shared__ __align__(16) char scratch[20480];
  int* soff = (int*)scratch;                        // [640][4]
  float* sw = (float*)(scratch + 10240);            // [640][4]
  float* wl = (float*)scratch;                      // [24][132]
  unsigned short* Hs = (unsigned short*)scratch;    // [16*512]

  int t = threadIdx.x;
  int m0 = blockIdx.x * 16;
  int r5 = t >> 5, cg5 = t & 31;
  int row5 = m0 + r5;
  int w = t >> 6, l = t & 63, la = l & 15, lb = l >> 4;
  int fl = *flagp;
  {
    float4 v = make_float4(0, 0, 0, 0);
    if (row5 < M) v = *(const float4*)(query + (size_t)row5 * 128 + cg5 * 4);
    *(float4*)&qtile[r5][cg5 * 4] = v;
  }
  __syncthreads();

  for (int L = 0; L < NCROSS; ++L) {
    const float* dpw = dpw_ + (size_t)L * 2048;
    const float* dpb = dpb_ + L * 16;
    const float* aw = aw_ + (size_t)L * 1024;
    const float* ab = ab_ + L * 8;
    const float* g1 = ln1g + L * 128;
    const float* be1 = ln1b + L * 128;
    // A1: stage proj weights
    for (int idx = t; idx < 24 * 128; idx += 512) {
      int c = idx >> 7, k = idx & 127;
      wl[c * 132 + k] = (c < 16) ? dpw[k * 16 + c] : aw[k * 8 + (c - 16)];
    }
    __syncthreads();
    // A2: LN + proj
    {
      float4 v = *(const float4*)&qtile[r5][cg5 * 4];
      float s1 = v.x + v.y + v.z + v.w;
      float s2 = v.x * v.x + v.y * v.y + v.z * v.z + v.w * v.w;
#pragma unroll
      for (int msk = 1; msk < 32; msk <<= 1) { s1 += __shfl_xor(s1, msk); s2 += __shfl_xor(s2, msk); }
      float mean = s1 * (1.f / 128.f);
      float var = s2 * (1.f / 128.f) - mean * mean;
      float inv = rsqrtf(var + 1e-5f);
      float lv[4] = {v.x, v.y, v.z, v.w};
      float ln4[4];
#pragma unroll
      for (int i = 0; i < 4; ++i) {
        int k = cg5 * 4 + i;
        ln4[i] = (lv[i] - mean) * inv * g1[k] + be1[k];
      }
      float p[24];
#pragma unroll
      for (int c = 0; c < 24; ++c) {
        float acc = 0.f;
#pragma unroll
        for (int i = 0; i < 4; ++i) acc += ln4[i] * wl[c * 132 + cg5 * 4 + i];
        p[c] = acc;
      }
#pragma unroll
      for (int msk = 1; msk < 32; msk <<= 1) {
#pragma unroll
        for (int c = 0; c < 24; ++c) p[c] += __shfl_xor(p[c], msk);
      }
      if (cg5 == 0) {
#pragma unroll
        for (int c = 0; c < 24; ++c) pr[r5][c] = p[c];
      }
    }
    __syncthreads();
    // A3: att softmax
    {
      int cc = cg5 & 7;
      float av = pr[r5][16 + cc] + ab[cc];
      float mx = av;
#pragma unroll
      for (int msk = 1; msk < 8; msk <<= 1) mx = fmaxf(mx, __shfl_xor(mx, msk));
      float e = expf(av - mx);
      float sm = e;
#pragma unroll
      for (int msk = 1; msk < 8; msk <<= 1) sm += __shfl_xor(sm, msk);
      if (cg5 < 8) attL[r5][cg5] = e / sm;
    }
    __syncthreads();
    // B1: offsets/weights
    for (int e = t; e < 640; e += 512) {
      int qi = e / 40, rem = e % 40;
      int n = rem >> 3, s = rem & 7;
      int row = m0 + qi;
      if (row >= M) {
#pragma unroll
        for (int c = 0; c < 4; ++c) { soff[e * 4 + c] = 0; sw[e * 4 + c] = 0.f; }
      } else {
        int b = row / QQ, q = row - b * QQ;
        int mi = (b * NCAM + n) * QQ + q;
        bool mk = mask_at(maskp, fl, mi);
        float a = mk ? attL[qi][s] : 0.f;
        float rx = refp[(size_t)mi * 2 + 0];
        float ry = refp[(size_t)mi * 2 + 1];
        float fx = (rx + pr[qi][s * 2 + 0] + dpb[s * 2 + 0]) * (float)(WFI - 1);
        float fy = (ry + pr[qi][s * 2 + 1] + dpb[s * 2 + 1]) * (float)(HFI - 1);
        float x0f = floorf(fx), y0f = floorf(fy);
        int x0 = (int)x0f, y0 = (int)y0f;
        float xd = fx - x0f, yd = fy - y0f;
        int base = (b * NCAM + n) * HWI;
#pragma unroll
        for (int cy = 0; cy < 2; ++cy)
#pragma unroll
          for (int cx = 0; cx < 2; ++cx) {
            int xi = x0 + cx, yi = y0 + cy;
            bool ok = (xi >= 0) & (xi < WFI) & (yi >= 0) & (yi < HFI);
            int xc = min(max(xi, 0), WFI - 1), yc = min(max(yi, 0), HFI - 1);
            soff[e * 4 + cy * 2 + cx] = (base + yc * WFI + xc) * 128;
            sw[e * 4 + cy * 2 + cx] = ok ? a * (cx ? xd : 1.f - xd) * (cy ? yd : 1.f - yd) : 0.f;
          }
      }
    }
    __syncthreads();
    // B2: gather (2 threads x 8ch halves per query via entry split)
    {
      int qi = t >> 5, sub = t & 31, ln = sub & 15, half = sub >> 4;
      float acc[8] = {};
      float wa = 0.f;
      for (int e = half * 20; e < half * 20 + 20; ++e) {
        int eb = qi * 40 + e;
        float4 wv = *(const float4*)&sw[eb * 4];
        float wsum = wv.x + wv.y + wv.z + wv.w;
        if (wsum != 0.f) {
          int4 ov = *(const int4*)&soff[eb * 4];
          s8v p0 = *(const s8v*)(imgT + (size_t)ov.x + ln * 8);
          s8v p1 = *(const s8v*)(imgT + (size_t)ov.y + ln * 8);
          s8v p2 = *(const s8v*)(imgT + (size_t)ov.z + ln * 8);
          s8v p3 = *(const s8v*)(imgT + (size_t)ov.w + ln * 8);
#pragma unroll
          for (int i = 0; i < 8; ++i)
            acc[i] += wv.x * bf2f((unsigned short)p0[i]) + wv.y * bf2f((unsigned short)p1[i])
                    + wv.z * bf2f((unsigned short)p2[i]) + wv.w * bf2f((unsigned short)p3[i]);
          wa += wsum;
        }
      }
#pragma unroll
      for (int i = 0; i < 8; ++i) acc[i] += __shfl_xor(acc[i], 16);
      wa += __shfl_xor(wa, 16);
      if (half == 0) {
        union { unsigned short u[8]; s8v v; } pk;
#pragma unroll
        for (int i = 0; i < 8; ++i) pk.u[i] = f2bf(acc[i]);
        *(s8v*)&As[qi * 128 + ((ln ^ (qi & 7)) << 3)] = pk.v;
        if (ln == 0) awa[qi] = wa;
      }
    }
    __syncthreads();
    // B3: op-GEMM + epilogue -> qtile
    {
      const unsigned short* Wc = WcT + (size_t)L * 16384;
      const float* v1L = v1_ + L * 128;
      const float* v2L = v2_ + L * 128;
      const float* opbL = opb_ + L * 128;
      f4 accm = {};
      int col = w * 16 + la;
#pragma unroll
      for (int ks = 0; ks < 4; ++ks) {
        s8v af = *(const s8v*)&As[la * 128 + (((ks * 4 + lb) ^ (la & 7)) << 3)];
        s8v bf = *(const s8v*)(Wc + (size_t)col * 128 + ks * 32 + lb * 8);
        accm = __builtin_amdgcn_mfma_f32_16x16x32_bf16(af, bf, accm, 0, 0, 0);
      }
#pragma unroll
      for (int j = 0; j < 4; ++j) {
        int lr = lb * 4 + j;
        int m = m0 + lr;
        if (m < M) {
          float s0m = invden[m];
          float val = accm[j] * s0m + s0m * awa[lr] * v1L[col] + imc[m] * v2L[col] + opbL[col];
          qtile[lr][col] += val;
        }
      }
    }
    __syncthreads();
    // C1: LN2 -> As (bf16, swizzled)
    {
      const float* g2 = ln2g + L * 128;
      const float* be2 = ln2b + L * 128;
      float4 v = *(const float4*)&qtile[r5][cg5 * 4];
      float s1 = v.x + v.y + v.z + v.w;
      float s2 = v.x * v.x + v.y * v.y + v.z * v.z + v.w * v.w;
#pragma unroll
      for (int msk = 1; msk < 32; msk <<= 1) { s1 += __shfl_xor(s1, msk); s2 += __shfl_xor(s2, msk); }
      float mean = s1 * (1.f / 128.f);
      float var = s2 * (1.f / 128.f) - mean * mean;
      float inv = rsqrtf(var + 1e-5f);
      float lv[4] = {v.x, v.y, v.z, v.w};
      union { unsigned short u[4]; ushort4 v4; } pk;
#pragma unroll
      for (int i = 0; i < 4; ++i) {
        int k = cg5 * 4 + i;
        pk.u[i] = f2bf((lv[i] - mean) * inv * g2[k] + be2[k]);
      }
      int c8 = cg5 >> 1, hf = cg5 & 1;
      *(ushort4*)&As[r5 * 128 + ((c8 ^ (r5 & 7)) << 3) + hf * 4] = pk.v4;
    }
    __syncthreads();
    // C2: ff1 + GELU -> Hs
    {
      const unsigned short* W1 = f1T + (size_t)L * 65536;
      const float* b1 = b1_ + L * 512;
      f4 acc1[4] = {};
#pragma unroll
      for (int ks = 0; ks < 4; ++ks) {
        s8v af = *(const s8v*)&As[la * 128 + (((ks * 4 + lb) ^ (la & 7)) << 3)];
#pragma unroll
        for (int ti = 0; ti < 4; ++ti) {
          int col = (w * 4 + ti) * 16 + la;
          s8v bf = *(const s8v*)(W1 + (size_t)col * 128 + ks * 32 + lb * 8);
          acc1[ti] = __builtin_amdgcn_mfma_f32_16x16x32_bf16(af, bf, acc1[ti], 0, 0, 0);
        }
      }
#pragma unroll
      for (int ti = 0; ti < 4; ++ti) {
        int col = (w * 4 + ti) * 16 + la;
        int chunk = col >> 3, idx = col & 7;
#pragma unroll
        for (int j = 0; j < 4; ++j) {
          int m = lb * 4 + j;
          float val = acc1[ti][j] + b1[col];
          val = 0.5f * val * (1.f + erff(val * 0.70710678118654752f));
          Hs[m * 512 + ((chunk ^ (m & 7)) << 3) + idx] = f2bf(val);
        }
      }
    }
    __syncthreads();
    // C3: ff2 + residual -> qtile
    {
      const unsigned short* W2 = f2T + (size_t)L * 65536;
      const float* b2 = b2_ + L * 128;
      f4 acc2 = {};
      int col = w * 16 + la;
#pragma unroll
      for (int ks = 0; ks < 16; ++ks) {
        s8v af = *(const s8v*)&Hs[la * 512 + (((ks * 4 + lb) ^ (la & 7)) << 3)];
        s8v bf = *(const s8v*)(W2 + (size_t)col * 512 + ks * 32 + lb * 8);
        acc2 = __builtin_amdgcn_mfma_f32_16x16x32_bf16(af, bf, acc2, 0, 0, 0);
      }
#pragma unroll
      for (int j = 0; j < 4; ++j) qtile[lb * 4 + j][col] += acc2[j] + b2[col];
    }
    __syncthreads();
  }
  if (row5 < M)
    *(float4*)(qb + (size_t)row5 * 128 + cg5 * 4) = *(const float4*)&qtile[r5][cg5 * 4];
}

// ================= SELF MEGA: 1 layer (scatter is global dep), optional classifier =================
template <bool CLS>
__global__ __launch_bounds__(512) void self_mega_k(
    const float* __restrict__ qbin, const float* __restrict__ ref3d,
    const unsigned short* __restrict__ vol, const float* __restrict__ many,
    const float* __restrict__ ln1g, const float* __restrict__ ln1b,
    const float* __restrict__ dpw, const float* __restrict__ dpb,
    const float* __restrict__ aw, const float* __restrict__ ab,
    const unsigned short* __restrict__ WcT, const float* __restrict__ opb,
    const float* __restrict__ csb,
    const float* __restrict__ ln2g, const float* __restrict__ ln2b,
    const unsigned short* __restrict__ f1T, const float* __restrict__ b1,
    const unsigned short* __restrict__ f2T, const float* __restrict__ b2,
    float* __restrict__ qb,
    const float* __restrict__ cw, const float* __restrict__ cb, float* __restrict__ out,
    int M) {
  __shared__ float qtile[16][128];
  __shared__ float pr[16][32];
  __shared__ float attL[16][8];
  __shared__ float gcL[16][24];
  __shared__ __align__(16) unsigned short As[16 * 128];
  __shared__ __align__(16) char scratch[20480];
  int* soff = (int*)scratch;                      // [128][8]
  float* sw = (float*)(scratch + 4096);           // [128][8]
  float* wl = (float*)scratch;                    // [32][132]
  unsigned short* Hs = (unsigned short*)scratch;  // [16*512]

  int t = threadIdx.x;
  int m0 = blockIdx.x * 16;
  int r5 = t >> 5, cg5 = t & 31;
  int row5 = m0 + r5;
  int w = t >> 6, l = t & 63, la = l & 15, lb = l >> 4;
  {
    float4 v = make_float4(0, 0, 0, 0);
    if (row5 < M) v = *(const float4*)(qbin + (size_t)row5 * 128 + cg5 * 4);
    *(float4*)&qtile[r5][cg5 * 4] = v;
  }
  // A1: stage proj weights
  for (int idx = t; idx < 32 * 128; idx += 512) {
    int c = idx >> 7, k = idx & 127;
    wl[c * 132 + k] = (c < 24) ? dpw[k * 24 + c] : aw[k * 8 + (c - 24)];
  }
  __syncthreads();
  // A2: LN + proj
  {
    float4 v = *(const float4*)&qtile[r5][cg5 * 4];
    float s1 = v.x + v.y + v.z + v.w;
    float s2 = v.x * v.x + v.y * v.y + v.z * v.z + v.w * v.w;
#pragma unroll
    for (int msk = 1; msk < 32; msk <<= 1) { s1 += __shfl_xor(s1, msk); s2 += __shfl_xor(s2, msk); }
    float mean = s1 * (1.f / 128.f);
    float var = s2 * (1.f / 128.f) - mean * mean;
    float inv = rsqrtf(var + 1e-5f);
    float lv[4] = {v.x, v.y, v.z, v.w};
    float ln4[4];
#pragma unroll
    for (int i = 0; i < 4; ++i) {
      int k = cg5 * 4 + i;
      ln4[i] = (lv[i] - mean) * inv * ln1g[k] + ln1b[k];
    }
    float p[32];
#pragma unroll
    for (int c = 0; c < 32; ++c) {
      float acc = 0.f;
#pragma unroll
      for (int i = 0; i < 4; ++i) acc += ln4[i] * wl[c * 132 + cg5 * 4 + i];
      p[c] = acc;
    }
#pragma unroll
    for (int msk = 1; msk < 32; msk <<= 1) {
#pragma unroll
      for (int c = 0; c < 32; ++c) p[c] += __shfl_xor(p[c], msk);
    }
    if (cg5 == 0) {
#pragma unroll
      for (int c = 0; c < 32; ++c) pr[r5][c] = p[c];
    }
  }
  __syncthreads();
  // A3: att softmax + coords (perm [1,0,2])
  {
    int cc = cg5 & 7;
    float av = pr[r5][24 + cc] + ab[cc];
    float mx = av;
#pragma unroll
    for (int msk = 1; msk < 8; msk <<= 1) mx = fmaxf(mx, __shfl_xor(mx, msk));
    float e = expf(av - mx);
    float sm = e;
#pragma unroll
    for (int msk = 1; msk < 8; msk <<= 1) sm += __shfl_xor(sm, msk);
    if (cg5 < 8) attL[r5][cg5] = e / sm;
  }
  if (t < 384) {
    int r = t / 24, tt = t % 24;
    int s = tt / 3, j = tt % 3;
    int pc = (j == 0) ? 1 : ((j == 1) ? 0 : 2);
    int row = m0 + r;
    float rv = (row < M) ? ref3d[row * 3 + pc] : 0.f;
    gcL[r][tt] = pr[r][s * 3 + pc] + dpb[s * 3 + pc] + rv;
  }
  __syncthreads();
  // B1: offsets
  if (t < 128) {
    int qi = t >> 3, s = t & 7;
    int row = m0 + qi;
    if (row >= M) {
#pragma unroll
      for (int c = 0; c < 8; ++c) { soff[t * 8 + c] = 0; sw[t * 8 + c] = 0.f; }
    } else {
      int b = row / QQ;
      float a = attL[qi][s];
      float fx = (gcL[qi][s * 3 + 0] + 1.f) * 0.5f * (float)(VZC - 1);
      float fy = (gcL[qi][s * 3 + 1] + 1.f) * 0.5f * (float)(VXC - 1);
      float fz = (gcL[qi][s * 3 + 2] + 1.f) * 0.5f * (float)(VYC - 1);
      float x0f = floorf(fx), y0f = floorf(fy), z0f = floorf(fz);
      int x0 = (int)x0f, y0 = (int)y0f, z0 = (int)z0f;
      float xd = fx - x0f, yd = fy - y0f, zd = fz - z0f;
      int base = b * NVOX;
#pragma unroll
      for (int cz = 0; cz < 2; ++cz)
#pragma unroll
        for (int cy = 0; cy < 2; ++cy)
#pragma unroll
          for (int cx = 0; cx < 2; ++cx) {
            int xi = x0 + cx, yi = y0 + cy, zi = z0 + cz;
            bool ok = (xi >= 0) & (xi < VZC) & (yi >= 0) & (yi < VXC) & (zi >= 0) & (zi < VYC);
            int xc = min(max(xi, 0), VZC - 1);
            int yc = min(max(yi, 0), VXC - 1);
            int zc = min(max(zi, 0), VYC - 1);
            int ci = cz * 4 + cy * 2 + cx;
            soff[t * 8 + ci] = (base + (zc * VXC + yc) * VZC + xc) * 128;
            sw[t * 8 + ci] = ok ? a * (cx ? xd : 1.f - xd) * (cy ? yd : 1.f - yd) * (cz ? zd : 1.f - zd) : 0.f;
          }
    }
  }
  __syncthreads();
  // B2: gather
  {
    int qi = t >> 5, sub = t & 31, ln = sub & 15, half = sub >> 4;
    float acc[8] = {};
    for (int s = half * 4; s < half * 4 + 4; ++s) {
      int eb = qi * 8 + s;
#pragma unroll
      for (int c = 0; c < 8; ++c) {
        float wgt = sw[eb * 8 + c];
        if (wgt != 0.f) {
          s8v p = *(const s8v*)(vol + (size_t)soff[eb * 8 + c] + ln * 8);
#pragma unroll
          for (int i = 0; i < 8; ++i) acc[i] += wgt * bf2f((unsigned short)p[i]);
        }
      }
    }
#pragma unroll
    for (int i = 0; i < 8; ++i) acc[i] += __shfl_xor(acc[i], 16);
    if (half == 0) {
      union { unsigned short u[8]; s8v v; } pk;
#pragma unroll
      for (int i = 0; i < 8; ++i) pk.u[i] = f2bf(acc[i]);
      *(s8v*)&As[qi * 128 + ((ln ^ (qi & 7)) << 3)] = pk.v;
    }
  }
  __syncthreads();
  // B3: op-GEMM + epilogue
  {
    f4 accm = {};
    int col = w * 16 + la;
#pragma unroll
    for (int ks = 0; ks < 4; ++ks) {
      s8v af = *(const s8v*)&As[la * 128 + (((ks * 4 + lb) ^ (la & 7)) << 3)];
      s8v bf = *(const s8v*)(WcT + (size_t)col * 128 + ks * 32 + lb * 8);
      accm = __builtin_amdgcn_mfma_f32_16x16x32_bf16(af, bf, accm, 0, 0, 0);
    }
#pragma unroll
    for (int j = 0; j < 4; ++j) {
      int lr = lb * 4 + j;
      int m = m0 + lr;
      if (m < M) {
        float s0m = many[m];
        qtile[lr][col] += accm[j] * s0m + s0m * csb[col] + opb[col];
      }
    }
  }
  __syncthreads();
  // C1: LN2 -> As
  {
    float4 v = *(const float4*)&qtile[r5][cg5 * 4];
    float s1 = v.x + v.y + v.z + v.w;
    float s2 = v.x * v.x + v.y * v.y + v.z * v.z + v.w * v.w;
#pragma unroll
    for (int msk = 1; msk < 32; msk <<= 1) { s1 += __shfl_xor(s1, msk); s2 += __shfl_xor(s2, msk); }
    float mean = s1 * (1.f / 128.f);
    float var = s2 * (1.f / 128.f) - mean * mean;
    float inv = rsqrtf(var + 1e-5f);
    float lv[4] = {v.x, v.y, v.z, v.w};
    union { unsigned short u[4]; ushort4 v4; } pk;
#pragma unroll
    for (int i = 0; i < 4; ++i) {
      int k = cg5 * 4 + i;
      pk.u[i] = f2bf((lv[i] - mean) * inv * ln2g[k] + ln2b[k]);
    }
    int c8 = cg5 >> 1, hf = cg5 & 1;
    *(ushort4*)&As[r5 * 128 + ((c8 ^ (r5 & 7)) << 3) + hf * 4] = pk.v4;
  }
  __syncthreads();
  // C2: ff1 + GELU -> Hs
  {
    f4 acc1[4] = {};
#pragma unroll
    for (int ks = 0; ks < 4; ++ks) {
      s8v af = *(const s8v*)&As[la * 128 + (((ks * 4 + lb) ^ (la & 7)) << 3)];
#pragma unroll
      for (int ti = 0; ti < 4; ++ti) {
        int col = (w * 4 + ti) * 16 + la;
        s8v bf = *(const s8v*)(f1T + (size_t)col * 128 + ks * 32 + lb * 8);
        acc1[ti] = __builtin_amdgcn_mfma_f32_16x16x32_bf16(af, bf, acc1[ti], 0, 0, 0);
      }
    }
#pragma unroll
    for (int ti = 0; ti < 4; ++ti) {
      int col = (w * 4 + ti) * 16 + la;
      int chunk = col >> 3, idx = col & 7;
#pragma unroll
      for (int j = 0; j < 4; ++j) {
        int m = lb * 4 + j;
        float val = acc1[ti][j] + b1[col];
        val = 0.5f * val * (1.f + erff(val * 0.70710678118654752f));
        Hs[m * 512 + ((chunk ^ (m & 7)) << 3) + idx] = f2bf(val);
      }
    }
  }
  __syncthreads();
  // C3: ff2 + residual
  {
    f4 acc2 = {};
    int col = w * 16 + la;
#pragma unroll
    for (int ks = 0; ks < 16; ++ks) {
      s8v af = *(const s8v*)&Hs[la * 512 + (((ks * 4 + lb) ^ (la & 7)) << 3)];
      s8v bf = *(const s8v*)(f2T + (size_t)col * 512 + ks * 32 + lb * 8);
      acc2 = __builtin_amdgcn_mfma_f32_16x16x32_bf16(af, bf, acc2, 0, 0, 0);
    }
#pragma unroll
    for (int j = 0; j < 4; ++j) qtile[lb * 4 + j][col] += acc2[j] + b2[col];
  }
  __syncthreads();
  if (CLS) {
    float ps0 = 0.f, ps1 = 0.f, ps2 = 0.f, ps3 = 0.f;
#pragma unroll
    for (int i = 0; i < 4; ++i) {
      int k = cg5 * 4 + i;
      float qv = qtile[r5][k];
      ps0 += qv * cw[k * 4 + 0];
      ps1 += qv * cw[k * 4 + 1];
      ps2 += qv * cw[k * 4 + 2];
      ps3 += qv * cw[k * 4 + 3];
    }
#pragma unroll
    for (int msk = 1; msk < 32; msk <<= 1) {
      ps0 += __shfl_xor(ps0, msk);
      ps1 += __shfl_xor(ps1, msk);
      ps2 += __shfl_xor(ps2, msk);
      ps3 += __shfl_xor(ps3, msk);
    }
    if (cg5 < 4 && row5 < M) {
      float o = (cg5 == 0) ? ps0 : (cg5 == 1) ? ps1 : (cg5 == 2) ? ps2 : ps3;
      out[row5 * 4 + cg5] = o + cb[cg5];
    }
  } else {
    if (row5 < M)
      *(float4*)(qb + (size_t)row5 * 128 + cg5 * 4) = *(const float4*)&qtile[r5][cg5 * 4];
  }
}

extern "C" void kernel_launch(void* const* d_in, const int* in_sizes, int n_in,
                              void* d_out, int out_size, void* d_ws, size_t ws_size,
                              hipStream_t stream) {
  (void)in_sizes; (void)n_in; (void)out_size; (void)ws_size;
  const float* query = (const float*)d_in[0];
  const float* ref_points = (const float*)d_in[1];
  const float* ref3d = (const float*)d_in[2];
  const float* imgf = (const float*)d_in[3];
  const unsigned char* maskp = (const unsigned char*)d_in[4];
  const int* x_idx = (const int*)d_in[5];
  const int* y_idx = (const int*)d_in[6];
  const int* z_idx = (const int*)d_in[7];
  const float* c_ln1_g = (const float*)d_in[8];
  const float* c_ln1_b = (const float*)d_in[9];
  const float* c_dp_w = (const float*)d_in[10];
  const float* c_dp_b = (const float*)d_in[11];
  const float* c_a_w = (const float*)d_in[12];
  const float* c_a_b = (const float*)d_in[13];
  const float* c_w_w = (const float*)d_in[14];
  const float* c_w_b = (const float*)d_in[15];
  const float* c_vp_w = (const float*)d_in[16];
  const float* c_vp_b = (const float*)d_in[17];
  const float* c_op_w = (const float*)d_in[18];
  const float* c_op_b = (const float*)d_in[19];
  const float* c_ln2_g = (const float*)d_in[20];
  const float* c_ln2_b = (const float*)d_in[21];
  const float* c_ff1_w = (const float*)d_in[22];
  const float* c_ff1_b = (const float*)d_in[23];
  const float* c_ff2_w = (const float*)d_in[24];
  const float* c_ff2_b = (const float*)d_in[25];
  const float* s_ln1_g = (const float*)d_in[26];
  const float* s_ln1_b = (const float*)d_in[27];
  const float* s_dp_w = (const float*)d_in[28];
  const float* s_dp_b = (const float*)d_in[29];
  const float* s_a_w = (const float*)d_in[30];
  const float* s_a_b = (const float*)d_in[31];
  const float* s_w_w = (const float*)d_in[32];
  const float* s_w_b = (const float*)d_in[33];
  const float* s_vp_w = (const float*)d_in[34];
  const float* s_vp_b = (const float*)d_in[35];
  const float* s_op_w = (const float*)d_in[36];
  const float* s_op_b = (const float*)d_in[37];
  const float* s_ln2_g = (const float*)d_in[38];
  const float* s_ln2_b = (const float*)d_in[39];
  const float* s_ff1_w = (const float*)d_in[40];
  const float* s_ff1_b = (const float*)d_in[41];
  const float* s_ff2_w = (const float*)d_in[42];
  const float* s_ff2_b = (const float*)d_in[43];
  const float* cls_w = (const float*)d_in[44];
  const float* cls_b = (const float*)d_in[45];
  float* out = (float*)d_out;

  char* ws = (char*)d_ws;
  size_t off = 0;
  auto carve = [&](size_t bytes) -> char* {
    char* p = ws + off;
    off += (bytes + 255) & ~(size_t)255;
    return p;
  };
  int* flag = (int*)carve(256);
  float* invden = (float*)carve(BQ * 4);
  float* imc = (float*)carve(BQ * 4);
  float* many = (float*)carve(BQ * 4);
  float* qb = (float*)carve((size_t)BQ * 128 * 4);
  int* winner = (int*)carve((size_t)BB * NVOX * 4);
  float* Qbuf = (float*)carve((size_t)5 * 16384 * 4);
  float* Wcbuf = (float*)carve((size_t)5 * 16384 * 4);
  unsigned short* WcT = (unsigned short*)carve((size_t)5 * 16384 * 2);
  unsigned short* f1T = (unsigned short*)carve((size_t)5 * 65536 * 2);
  unsigned short* f2T = (unsigned short*)carve((size_t)5 * 65536 * 2);
  float* v1buf = (float*)carve(3 * 128 * 4);
  float* v2buf = (float*)carve(3 * 128 * 4);
  float* csbuf = (float*)carve(2 * 128 * 4);
  unsigned short* imgT = (unsigned short*)carve((size_t)BB * NCAM * HWI * 128 * 2);
  unsigned short* vol = (unsigned short*)carve((size_t)BB * NVOX * 128 * 2);

  const int M = BQ;
  const int GB16 = (M + 15) / 16;  // 313

  // ---- setup (7 launches) ----
  mask_k<<<1, 1024, 0, stream>>>(maskp, flag, invden, imc, many);
  tpre_k<<<dim3(2, 2, 165), 256, 0, stream>>>(c_w_w, s_w_w, c_op_w, s_op_w,
                                              c_ff1_w, s_ff1_w, c_ff2_w, s_ff2_w,
                                              Qbuf, f1T, f2T);
  {
    P5 pw;
    for (int L = 0; L < 5; ++L) {
      pw.a[L] = (L < 3) ? c_vp_w + (size_t)L * 16384 : s_vp_w + (size_t)(L - 3) * 16384;
      pw.b[L] = Qbuf + (size_t)L * 16384;
      pw.c[L] = Wcbuf + (size_t)L * 16384;
    }
    small_mm_k<<<dim3(2, 2, 5), 256, 0, stream>>>(pw);
  }
  wpre_k<<<dim3(16, 6), 256, 0, stream>>>(Wcbuf, WcT, c_vp_b, c_w_b, s_vp_b, s_w_b,
                                          c_op_w, s_op_w, Qbuf, v1buf, v2buf, csbuf);
  transpose_img_k<<<dim3((HWI + 63) / 64, 4, BB * NCAM), 256, 0, stream>>>(imgf, imgT);
  zero_vol_k<<<1024, 256, 0, stream>>>(vol, winner);
  scatter_winner_k<<<(BQ + 255) / 256, 256, 0, stream>>>(x_idx, y_idx, z_idx, winner);

  // ---- cross stack: ONE kernel, 3 layers ----
  cross_mega_k<<<GB16, 512, 0, stream>>>(query, ref_points, maskp, flag, invden, imc, imgT,
                                         c_ln1_g, c_ln1_b, c_dp_w, c_dp_b, c_a_w, c_a_b,
                                         WcT, c_op_b, v1buf, v2buf, c_ln2_g, c_ln2_b,
                                         f1T, c_ff1_b, f2T, c_ff2_b, qb, M);

  // ---- self stack ----
  scatter_write_k<<<(BQ * 16 + 255) / 256, 256, 0, stream>>>(x_idx, y_idx, z_idx, winner, qb, vol);
  self_mega_k<false><<<GB16, 512, 0, stream>>>(qb, ref3d, vol, many,
                                               s_ln1_g, s_ln1_b, s_dp_w, s_dp_b, s_a_w, s_a_b,
                                               WcT + (size_t)3 * 16384, s_op_b, csbuf,
                                               s_ln2_g, s_ln2_b,
                                               f1T + (size_t)3 * 65536, s_ff1_b,
                                               f2T + (size_t)3 * 65536, s_ff2_b,
                                               qb, cls_w, cls_b, out, M);
  scatter_write_k<<<(BQ * 16 + 255) / 256, 256, 0, stream>>>(x_idx, y_idx, z_idx, winner, qb, vol);
  self_mega_k<true><<<GB16, 512, 0, stream>>>(qb, ref3d, vol, many,
                                              s_ln1_g + 128, s_ln1_b + 128,
                                              s_dp_w + (size_t)128 * 24, s_dp_b + 24,
                                              s_a_w + (size_t)128 * 8, s_a_b + 8,
                                              WcT + (size_t)4 * 16384, s_op_b + 128,
                                              csbuf + 128, s_ln2_g + 128, s_ln2_b + 128,
                                              f1T + (size_t)4 * 65536, s_ff1_b + 512,
                                              f2T + (size_t)4 * 65536, s_ff2_b + 128,
                                              qb, cls_w, cls_b, out, M);
}